// Round 7
// baseline (1038.527 us; speedup 1.0000x reference)
//
#include <hip/hip_runtime.h>

typedef unsigned int u32;
typedef unsigned short u16;
typedef unsigned long long u64;
typedef _Float16 h2 __attribute__((ext_vector_type(2)));
typedef _Float16 h4 __attribute__((ext_vector_type(4)));
typedef _Float16 h8 __attribute__((ext_vector_type(8)));
typedef float f4 __attribute__((ext_vector_type(4)));

#define ROWS 65536   // B*A
#define NB 1024
#define NA 64

__device__ __forceinline__ float dot4(float4 w, float4 x){
  return w.x*x.x + w.y*x.y + w.z*x.z + w.w*x.w;
}
__device__ __forceinline__ h2 u32_h2(u32 v){ union { u32 u; h2 h; } x; x.u = v; return x.h; }
__device__ __forceinline__ h2 pack_h2(float a, float b){ h2 r; r.x = (_Float16)a; r.y = (_Float16)b; return r; }
__device__ __forceinline__ h4 pack_h4(float4 v){
  h4 r; r.x=(_Float16)v.x; r.y=(_Float16)v.y; r.z=(_Float16)v.z; r.w=(_Float16)v.w; return r;
}
__device__ __forceinline__ h4 pack_h4_relu(float4 v){
  h4 r; r.x=(_Float16)fmaxf(v.x,0.f); r.y=(_Float16)fmaxf(v.y,0.f);
  r.z=(_Float16)fmaxf(v.z,0.f); r.w=(_Float16)fmaxf(v.w,0.f); return r;
}
// fast sigmoid/tanh on v_exp_f32 + v_rcp_f32 (~1 ulp each; threshold is 1.1e-2)
__device__ __forceinline__ float fsig(float z){
  float e = __builtin_amdgcn_exp2f(-1.44269504f * z);
  return __builtin_amdgcn_rcpf(1.0f + e);
}
__device__ __forceinline__ float ftanh(float z){
  float e = __builtin_amdgcn_exp2f(2.885390082f * z);
  return 1.0f - 2.0f * __builtin_amdgcn_rcpf(1.0f + e);
}
__device__ __forceinline__ h8 load8f(const float* p){
  float4 a = *(const float4*)p;
  float4 b = *(const float4*)(p + 4);
  h8 r;
  r[0] = (_Float16)a.x; r[1] = (_Float16)a.y; r[2] = (_Float16)a.z; r[3] = (_Float16)a.w;
  r[4] = (_Float16)b.x; r[5] = (_Float16)b.y; r[6] = (_Float16)b.z; r[7] = (_Float16)b.w;
  return r;
}
__device__ __forceinline__ float bperm_f(int addr, float v){
  return __int_as_float(__builtin_amdgcn_ds_bpermute(addr, __float_as_int(v)));
}

// ---------------- weight f16 pre-convert (actor_2 weights) ----------------
__global__ __launch_bounds__(256) void k_cvt(
    const float* __restrict__ a2w1, const float* __restrict__ a2w2,
    _Float16* __restrict__ w1h, _Float16* __restrict__ w2h)
{
  int i = blockIdx.x * 256 + threadIdx.x;
  if (i < 32768) w1h[i] = (_Float16)a2w1[i];
  if (i < 8192)  w2h[i] = (_Float16)a2w2[i];
}

// ---------------- actor_1 + attention: 8 rows per block, 128 threads ----------------
// kept f32/VALU: feeds the DISCRETE decisions (isinit threshold, K-nearest argsort) where
// f16 rounding (~1e-3) could flip group membership and blow up absmax.
__global__ __launch_bounds__(128) void k_actor1(
    const float* __restrict__ obs, const float* __restrict__ w1, const float* __restrict__ b1,
    const float* __restrict__ lng, const float* __restrict__ lnb,
    const float* __restrict__ w2, const float* __restrict__ b2,
    const float* __restrict__ aw1, const float* __restrict__ ab1,
    const float* __restrict__ aw2, const float* __restrict__ ab2,
    const float* __restrict__ aw3, const float* __restrict__ ab3,
    float* __restrict__ thoughts, int* __restrict__ isinit)
{
  const int b0 = blockIdx.x * 8;
  const int t = threadIdx.x;
  __shared__ float4 xs[8][64];     // 8 obs rows (256 f32 each)
  __shared__ float hs[8][128];     // relu(LN(h))
  __shared__ float tb[8][128];     // thoughts
  __shared__ float ab[8][64];
  __shared__ float a2b[8][64];
  __shared__ float red[8][4];

  { const float4* og = (const float4*)(obs + (size_t)b0 * 256);
    #pragma unroll
    for (int j = 0; j < 4; j++){ int p = j * 128 + t; xs[p >> 6][p & 63] = og[p]; } }
  __syncthreads();

  // h = obs @ W1^T + b1   (thread t owns output feature t, streams W1 row t)
  float acc[8];
  #pragma unroll
  for (int r = 0; r < 8; r++) acc[r] = b1[t];
  { const float4* wr = (const float4*)(w1 + (size_t)t * 256);
    for (int j = 0; j < 64; j++){
      float4 w = wr[j];
      #pragma unroll
      for (int r = 0; r < 8; r++) acc[r] += dot4(w, xs[r][j]);
    } }

  // LayerNorm over 128 features (block = 2 waves)
  #pragma unroll
  for (int r = 0; r < 8; r++){
    float s = acc[r], s2 = acc[r] * acc[r];
    #pragma unroll
    for (int off = 32; off > 0; off >>= 1){ s += __shfl_down(s, off); s2 += __shfl_down(s2, off); }
    if ((t & 63) == 0){ red[r][t >> 6] = s; red[r][2 + (t >> 6)] = s2; }
  }
  __syncthreads();
  const float g_ = lng[t], bb_ = lnb[t];
  #pragma unroll
  for (int r = 0; r < 8; r++){
    float mu  = (red[r][0] + red[r][1]) * (1.0f/128.0f);
    float var = (red[r][2] + red[r][3]) * (1.0f/128.0f) - mu * mu;
    hs[r][t] = fmaxf((acc[r] - mu) * rsqrtf(var + 1e-5f) * g_ + bb_, 0.0f);
  }
  __syncthreads();

  // thoughts = relu(h) @ W2^T + b2
  float acc2[8];
  #pragma unroll
  for (int r = 0; r < 8; r++) acc2[r] = b2[t];
  { const float4* wr = (const float4*)(w2 + (size_t)t * 128);
    for (int j = 0; j < 32; j++){
      float4 w = wr[j];
      #pragma unroll
      for (int r = 0; r < 8; r++) acc2[r] += dot4(w, ((const float4*)hs[r])[j]);
    } }
  #pragma unroll
  for (int r = 0; r < 8; r++){
    thoughts[(size_t)(b0 + r) * 128 + t] = acc2[r];
    tb[r][t] = acc2[r];
  }
  __syncthreads();

  // attention MLP
  if (t < 64){
    float a[8];
    #pragma unroll
    for (int r = 0; r < 8; r++) a[r] = ab1[t];
    const float4* wr = (const float4*)(aw1 + (size_t)t * 128);
    for (int j = 0; j < 32; j++){
      float4 w = wr[j];
      #pragma unroll
      for (int r = 0; r < 8; r++) a[r] += dot4(w, ((const float4*)tb[r])[j]);
    }
    #pragma unroll
    for (int r = 0; r < 8; r++) ab[r][t] = fmaxf(a[r], 0.0f);
  }
  __syncthreads();
  if (t < 64){
    float a[8];
    #pragma unroll
    for (int r = 0; r < 8; r++) a[r] = ab2[t];
    const float4* wr = (const float4*)(aw2 + (size_t)t * 64);
    for (int j = 0; j < 16; j++){
      float4 w = wr[j];
      #pragma unroll
      for (int r = 0; r < 8; r++) a[r] += dot4(w, ((const float4*)ab[r])[j]);
    }
    #pragma unroll
    for (int r = 0; r < 8; r++) a2b[r][t] = fmaxf(a[r], 0.0f);
  }
  __syncthreads();
  if (t < 8){
    float p = ab3[0];
    for (int j = 0; j < 64; j++) p += aw3[j] * a2b[t][j];
    isinit[b0 + t] = (p > 0.0f) ? 1 : 0;   // sigmoid(p) > 0.5  <=>  p > 0
  }
}

// ---------------- K-nearest groups: one block per batch ----------------
__global__ __launch_bounds__(256) void k_groups(
    const float* __restrict__ thoughts, int* __restrict__ idxout)
{
  const int b = blockIdx.x;
  const int tid = threadIdx.x;
  __shared__ float T[64 * 130];
  __shared__ float sq[64];
  for (int p = tid; p < 8192; p += 256){
    T[(p >> 7) * 130 + (p & 127)] = thoughts[(size_t)b * 8192 + p];
  }
  __syncthreads();
  if (tid < 64){
    const float2* tj = (const float2*)&T[tid * 130];
    float s = 0.0f;
    #pragma unroll 8
    for (int k = 0; k < 64; k++){ float2 v = tj[k]; s += v.x*v.x + v.y*v.y; }
    sq[tid] = s;
  }
  __syncthreads();
  const int lane = tid & 63;
  const int wv = tid >> 6;
  const float2* tj = (const float2*)&T[lane * 130];
  const float sqj = sq[lane];
  for (int ii = 0; ii < 16; ii++){
    const int i = wv * 16 + ii;
    const float2* ti = (const float2*)&T[i * 130];
    float dot = 0.0f;
    #pragma unroll 8
    for (int k = 0; k < 64; k++){ float2 a = ti[k]; float2 c = tj[k]; dot += a.x*c.x + a.y*c.y; }
    float d = fmaxf(sq[i] + sqj - 2.0f*dot, 0.0f);   // clamp keeps uint-compare == float-compare
    u64 key = (((u64)__float_as_uint(d)) << 32) | (u32)lane;
    u64 mask = 0;
    for (int q = 0; q < 8; q++){
      u64 m = key;
      #pragma unroll
      for (int off = 32; off > 0; off >>= 1){ u64 o = __shfl_xor(m, off); if (o < m) m = o; }
      mask |= 1ull << (u32)(m & 63u);
      if (key == m) key = ~0ull;
    }
    if (lane == 0){
      u64 mm = mask;
      int base = (b * 64 + i) * 8;
      #pragma unroll
      for (int q = 0; q < 8; q++){ int j = (int)__builtin_ctzll(mm); mm &= mm - 1; idxout[base + q] = j; }
    }
  }
}

// ---------------- sequential gather -> bi-LSTM -> scatter: TWO batches per block ----------------
// v8 = barrier-free recurrence (v5/v6 machinery, both correctness-verified) x 2-batch packing
// (v7). 8 waves, 1 block/CU:
//  * waves 0-3 = RECURRENCE waves, role (q = w&1, dir = w>>1): each owns the full 8-step
//    recurrence for one (batch,dir). Lane l holds h-row l; h redistributes to the MFMA
//    A-fragment layout in-register via 16 ds_bpermute (v5, verified r4). Per step: 32 MFMA
//    immediate-consume via the hi==lt select (v6, verified r5). ZERO barriers in the 8 steps;
//    4 busy SIMDs (fixes v6's 1-SIMD concentration).
//  * waves 4-7 = PHASE-A waves, role (dir = (w-4)>>1, half = (w-4)&1): Zx = bias + X @ Wih^T
//    with v7's 2-batch A-row packing (rows 0-7 = batch0, 8-15 = batch1); 8 coltiles each.
//  * W[32] register union: A-waves hold Wih fragments, B-waves hold Whh fragments (128 VGPR
//    each, symmetric); __launch_bounds__(512,2) -> 256-reg cap, unified VGPR/AGPR absorbs it
//    (v6: no spill at similar demand). Barriers per active initiator: 2 (was 9 in v7).
// MFMA conventions (verified v3-v7): A row = lane&15, B col = lane&15,
// k = kt*32 + (lane>>4)*8 + j, C: col = lane&15, row = (lane>>4)*4 + reg.
__global__ __launch_bounds__(512, 2) void k_scan(
    const float* __restrict__ thoughts, const int* __restrict__ isinit, const int* __restrict__ idx,
    const float* __restrict__ wihf, const float* __restrict__ whhf,
    const float* __restrict__ bihf, const float* __restrict__ bhhf,
    const float* __restrict__ wihb, const float* __restrict__ whhb,
    const float* __restrict__ bihb, const float* __restrict__ bhhb,
    float* __restrict__ newt)
{
  const int b0   = blockIdx.x * 2;
  const int tid  = threadIdx.x;
  const int w    = tid >> 6;          // wave 0..7
  const int lane = tid & 63;
  const int lr   = lane & 15;
  const int hi   = lane >> 4;
  const bool isB = (w < 4);
  const int qB   = w & 1;             // recurrence: batch
  const int dirB = (w >> 1) & 1;      // recurrence: direction
  const int aw   = w - 4;
  const int dirA = (aw >> 1) & 1;     // phase A: direction
  const int half = aw & 1;            // phase A: coltile half (ct 0-7 / 8-15)

  __shared__ __align__(16) _Float16 nt16[2][64 * 136]; // f16 state mirrors (2 x 17408 B)
  __shared__ __align__(16) _Float16 Zx16[2][2*8*64*4]; // input projections (2 x 8192 B)
  __shared__ int gall[2][512];
  __shared__ int flags[2][64];
  __shared__ int dirty[2][64];

  // ---- weight fragments (register union) ----
  h8 W[32];
  float biasl[8];
  if (isB){
    const float* whh = dirB ? whhb : whhf;
    #pragma unroll
    for (int ct = 0; ct < 16; ct++){
      const int n = ((ct >> 2) << 6) + ((ct & 3) << 4) + lr;
      const float* wr = whh + (size_t)n * 64 + (hi << 3);
      W[ct * 2 + 0] = load8f(wr);
      W[ct * 2 + 1] = load8f(wr + 32);
      __builtin_amdgcn_sched_barrier(0);
    }
  } else {
    const float* wih = dirA ? wihb : wihf;
    const float* bih = dirA ? bihb : bihf;
    const float* bhh = dirA ? bhhb : bhhf;
    #pragma unroll
    for (int k = 0; k < 8; k++){
      const int ct = (half << 3) + k;
      const int n = ((ct >> 2) << 6) + ((ct & 3) << 4) + lr;
      const float* wr = wih + (size_t)n * 128 + (hi << 3);
      #pragma unroll
      for (int kt = 0; kt < 4; kt++) W[k * 4 + kt] = load8f(wr + kt * 32);
      biasl[k] = bih[n] + bhh[n];
      __builtin_amdgcn_sched_barrier(0);
    }
  }

  #pragma unroll
  for (int q = 0; q < 2; q++){
    const float4* tf4 = (const float4*)(thoughts + (size_t)(b0 + q) * 8192);
    #pragma unroll
    for (int k2 = 0; k2 < 4; k2++){
      int id4 = tid + k2 * 512;                 // f4 index, 2048 per batch (32 f4 per row)
      float4 v = tf4[id4];
      *(h4*)&nt16[q][(id4 >> 5) * 136 + (id4 & 31) * 4] = pack_h4(v);
    }
  }
  { int p = tid;              gall[0][p] = idx[(size_t)b0 * 512 + p]; }
  { int p = tid + 512;        gall[1][p - 512] = idx[(size_t)b0 * 512 + p]; }
  if (tid < 128){ int q = tid >> 6, j = tid & 63;
    flags[q][j] = isinit[(b0 + q) * 64 + j]; dirty[q][j] = 0; }
  __syncthreads();

  #pragma unroll 1
  for (int i = 0; i < 64; i++){
    const int f0 = flags[0][i], f1 = flags[1][i];
    if (!(f0 | f1)) continue;           // block-uniform
    if (tid < 16){ int q = tid >> 3, j = tid & 7;
      if (q ? f1 : f0) dirty[q][gall[q][i * 8 + j]] = 1; }

    // ---- phase A (waves 4-7): Zx[q] = bias + X[q] @ Wih^T; A rows 0-7=b0, 8-15=b1 ----
    if (!isB){
      const int qa = lr >> 3;
      const int grow = gall[qa][i * 8 + (lr & 7)];
      h8 Af[4];
      #pragma unroll
      for (int kt = 0; kt < 4; kt++)
        Af[kt] = *(const h8*)&nt16[qa][grow * 136 + kt * 32 + (hi << 3)];
      const int qo = hi >> 1, t0 = (hi & 1) << 2;      // C rows hi*4..+3 -> (qo, t0..t0+3)
      #pragma unroll
      for (int k = 0; k < 8; k++){
        const int ct = (half << 3) + k;
        const int g = ct >> 2, lp = ((ct & 3) << 4) + lr;
        f4 acc = {0.0f, 0.0f, 0.0f, 0.0f};
        #pragma unroll
        for (int kt = 0; kt < 4; kt++)
          acc = __builtin_amdgcn_mfma_f32_16x16x32_f16(Af[kt], W[k * 4 + kt], acc, 0, 0, 0);
        #pragma unroll
        for (int r = 0; r < 4; r++)
          Zx16[qo][(((dirA << 3) + t0 + r) * 64 + lp) * 4 + g] = (_Float16)(acc[r] + biasl[k]);
      }
    }
    __syncthreads();

    // ---- phase B (waves 0-3): 8-step recurrence, ZERO barriers ----
    if (isB && (qB ? f1 : f0)){
      float c = 0.0f;
      h8 a0 = {}, a1 = {};               // h in A-fragment layout (set at end of each step)
      #pragma unroll 1
      for (int s = 0; s < 8; s++){
        const int tt = dirB ? (7 - s) : s;
        uint2 zr = *(const uint2*)&Zx16[qB][(((dirB << 3) + tt) * 64 + lane) * 4];
        h2 zlo = u32_h2(zr.x), zhi2 = u32_h2(zr.y);
        float z0 = (float)zlo.x, z1 = (float)zlo.y, z2 = (float)zhi2.x, z3 = (float)zhi2.y;
        if (s > 0){
          float za[4];
          #pragma unroll
          for (int g = 0; g < 4; g++){
            float zs = 0.0f;
            #pragma unroll
            for (int lt = 0; lt < 4; lt++){
              f4 t = {0.0f, 0.0f, 0.0f, 0.0f};
              t = __builtin_amdgcn_mfma_f32_16x16x32_f16(a0, W[(g * 4 + lt) * 2 + 0], t, 0, 0, 0);
              t = __builtin_amdgcn_mfma_f32_16x16x32_f16(a1, W[(g * 4 + lt) * 2 + 1], t, 0, 0, 0);
              zs = (hi == lt) ? t[0] : zs;
            }
            za[g] = zs;
          }
          z0 += za[0]; z1 += za[1]; z2 += za[2]; z3 += za[3];
        }
        // gates (i,f,g,o); lane owns h-row l = lane
        float fi = fsig(z0);
        float ff = fsig(z1);
        float fg = ftanh(z2);
        float fo = fsig(z3);
        c = ff * c + fi * fg;
        float hn = fo * ftanh(c);
        // scatter into state mirror (row uniform across wave; cols disjoint per dir)
        nt16[qB][gall[qB][i * 8 + tt] * 136 + (dirB << 6) + lane] = (_Float16)hn;
        if (s < 7){
          // in-register h redistribution: A-frag k = kt*32 + hi*8 + j, h[k] lives at lane k
          const int ab = hi << 5;        // 4 * (hi*8)
          float p0 = bperm_f(ab +  0, hn), p1 = bperm_f(ab +  4, hn);
          float p2 = bperm_f(ab +  8, hn), p3 = bperm_f(ab + 12, hn);
          float p4 = bperm_f(ab + 16, hn), p5 = bperm_f(ab + 20, hn);
          float p6 = bperm_f(ab + 24, hn), p7 = bperm_f(ab + 28, hn);
          float q0 = bperm_f(ab + 128, hn), q1 = bperm_f(ab + 132, hn);
          float q2 = bperm_f(ab + 136, hn), q3 = bperm_f(ab + 140, hn);
          float q4 = bperm_f(ab + 144, hn), q5 = bperm_f(ab + 148, hn);
          float q6 = bperm_f(ab + 152, hn), q7 = bperm_f(ab + 156, hn);
          a0[0]=(_Float16)p0; a0[1]=(_Float16)p1; a0[2]=(_Float16)p2; a0[3]=(_Float16)p3;
          a0[4]=(_Float16)p4; a0[5]=(_Float16)p5; a0[6]=(_Float16)p6; a0[7]=(_Float16)p7;
          a1[0]=(_Float16)q0; a1[1]=(_Float16)q1; a1[2]=(_Float16)q2; a1[3]=(_Float16)q3;
          a1[4]=(_Float16)q4; a1[5]=(_Float16)q5; a1[6]=(_Float16)q6; a1[7]=(_Float16)q7;
        }
      }
    }
    __syncthreads();
  }

  __syncthreads();
  #pragma unroll
  for (int q = 0; q < 2; q++){
    const float4* tf4 = (const float4*)(thoughts + (size_t)(b0 + q) * 8192);
    float4* of4 = (float4*)(newt + (size_t)(b0 + q) * 8192);
    #pragma unroll
    for (int k2 = 0; k2 < 4; k2++){
      int id4 = tid + k2 * 512;
      int row = id4 >> 5, c4 = (id4 & 31) * 4;
      float4 v = tf4[id4];
      if (dirty[q][row]){
        h4 hv = *(const h4*)&nt16[q][row * 136 + c4];
        v.x = (float)hv.x; v.y = (float)hv.y; v.z = (float)hv.z; v.w = (float)hv.w;
      }
      of4[id4] = v;
    }
  }
}

// ---------------- actor_2 (MFMA f16): 32 rows per block, 256 threads ----------------
// x = relu(concat(thoughts,newt)) (32x256) @ a2w1^T (256->128) + b1 -> (32x128) @ a2w2^T
// (128->64) -> tanh. f16 inputs/weights, f32 accum; no discrete decisions downstream.
__global__ __launch_bounds__(256) void k_actor2(
    const float* __restrict__ thoughts, const float* __restrict__ newt,
    const _Float16* __restrict__ w1h, const float* __restrict__ b1,
    const _Float16* __restrict__ w2h, float* __restrict__ out)
{
  const int b0 = blockIdx.x * 32;
  const int tid = threadIdx.x;
  const int w = tid >> 6, lane = tid & 63, lr = lane & 15, hi = lane >> 4;
  const int mt = w & 1, nb = (w >> 1) << 6;

  __shared__ __align__(16) _Float16 Xc[32 * 264];   // relu(concat) f16, padded (16896 B)
  __shared__ __align__(16) _Float16 Ys[32 * 136];   // hidden f16, padded (8704 B)

  #pragma unroll
  for (int k2 = 0; k2 < 8; k2++){
    int id4 = tid + k2 * 256;              // f4 index over 32 rows x 64 f4
    int row = id4 >> 6, c4 = (id4 & 63) * 4;
    const float* src = (c4 < 128) ? (thoughts + (size_t)(b0 + row) * 128 + c4)
                                  : (newt + (size_t)(b0 + row) * 128 + (c4 - 128));
    float4 v = *(const float4*)src;
    *(h4*)&Xc[row * 264 + c4] = pack_h4_relu(v);
  }
  __syncthreads();

  // GEMM1: wave (mt, nb): rows mt*16.., cols nb..nb+63
  {
    h8 Af[8];
    #pragma unroll
    for (int kt = 0; kt < 8; kt++)
      Af[kt] = *(const h8*)&Xc[(mt * 16 + lr) * 264 + kt * 32 + (hi << 3)];
    #pragma unroll
    for (int ni = 0; ni < 4; ni++){
      const int n = nb + ni * 16 + lr;
      const _Float16* wr = w1h + (size_t)n * 256 + (hi << 3);
      f4 acc = {0.0f, 0.0f, 0.0f, 0.0f};
      #pragma unroll
      for (int kt = 0; kt < 8; kt++){
        h8 bfr = *(const h8*)(wr + kt * 32);
        acc = __builtin_amdgcn_mfma_f32_16x16x32_f16(Af[kt], bfr, acc, 0, 0, 0);
      }
      const float bb = b1[n];
      #pragma unroll
      for (int r = 0; r < 4; r++){
        int row = mt * 16 + (hi << 2) + r;
        Ys[row * 136 + n] = (_Float16)(acc[r] + bb);
      }
    }
  }
  __syncthreads();

  // GEMM2: wave (mt, ni0): rows mt*16.., cols (ni0..ni0+1)*16
  {
    const int ni0 = (w >> 1) << 1;
    h8 Ag[4];
    #pragma unroll
    for (int kt = 0; kt < 4; kt++)
      Ag[kt] = *(const h8*)&Ys[(mt * 16 + lr) * 136 + kt * 32 + (hi << 3)];
    #pragma unroll
    for (int nj = 0; nj < 2; nj++){
      const int n = (ni0 + nj) * 16 + lr;
      const _Float16* wr = w2h + (size_t)n * 128 + (hi << 3);
      f4 acc = {0.0f, 0.0f, 0.0f, 0.0f};
      #pragma unroll
      for (int kt = 0; kt < 4; kt++){
        h8 bfr = *(const h8*)(wr + kt * 32);
        acc = __builtin_amdgcn_mfma_f32_16x16x32_f16(Ag[kt], bfr, acc, 0, 0, 0);
      }
      #pragma unroll
      for (int r = 0; r < 4; r++){
        int row = mt * 16 + (hi << 2) + r;
        out[(size_t)(b0 + row) * 64 + n] = ftanh(acc[r]);
      }
    }
  }
}

extern "C" void kernel_launch(void* const* d_in, const int* in_sizes, int n_in,
                              void* d_out, int out_size, void* d_ws, size_t ws_size,
                              hipStream_t stream)
{
  const float* obs  = (const float*)d_in[0];
  const float* w1   = (const float*)d_in[1];
  const float* b1   = (const float*)d_in[2];
  const float* lng  = (const float*)d_in[3];
  const float* lnb  = (const float*)d_in[4];
  const float* w2   = (const float*)d_in[5];
  const float* b2   = (const float*)d_in[6];
  const float* aw1  = (const float*)d_in[7];
  const float* ab1  = (const float*)d_in[8];
  const float* aw2  = (const float*)d_in[9];
  const float* ab2  = (const float*)d_in[10];
  const float* aw3  = (const float*)d_in[11];
  const float* ab3  = (const float*)d_in[12];
  const float* wihf = (const float*)d_in[13];
  const float* whhf = (const float*)d_in[14];
  const float* bihf = (const float*)d_in[15];
  const float* bhhf = (const float*)d_in[16];
  const float* wihb = (const float*)d_in[17];
  const float* whhb = (const float*)d_in[18];
  const float* bihb = (const float*)d_in[19];
  const float* bhhb = (const float*)d_in[20];
  const float* a2w1 = (const float*)d_in[21];
  const float* a2b1 = (const float*)d_in[22];
  const float* a2w2 = (const float*)d_in[23];

  float* thoughts = (float*)d_ws;                       // 33.5 MB
  float* newt     = thoughts + (size_t)ROWS * 128;      // 33.5 MB
  int*   isinit   = (int*)(newt + (size_t)ROWS * 128);  // 256 KB
  int*   idxb     = isinit + ROWS;                      // 2 MB
  _Float16* w1h   = (_Float16*)(idxb + (size_t)ROWS * 8);  // 64 KB
  _Float16* w2h   = w1h + 32768;                           // 16 KB

  hipLaunchKernelGGL(k_cvt, dim3(128), dim3(256), 0, stream, a2w1, a2w2, w1h, w2h);
  hipLaunchKernelGGL(k_actor1, dim3(ROWS / 8), dim3(128), 0, stream,
                     obs, w1, b1, lng, lnb, w2, b2, aw1, ab1, aw2, ab2, aw3, ab3,
                     thoughts, isinit);
  hipLaunchKernelGGL(k_groups, dim3(NB), dim3(256), 0, stream, thoughts, idxb);
  hipLaunchKernelGGL(k_scan, dim3(NB / 2), dim3(512), 0, stream,
                     thoughts, isinit, idxb,
                     wihf, whhf, bihf, bhhf, wihb, whhb, bihb, bhhb, newt);
  hipLaunchKernelGGL(k_actor2, dim3(ROWS / 32), dim3(256), 0, stream,
                     thoughts, newt, w1h, a2b1, w2h, (float*)d_out);
}

// Round 8
// 923.517 us; speedup vs baseline: 1.1245x; 1.1245x over previous
//
#include <hip/hip_runtime.h>

typedef unsigned int u32;
typedef unsigned short u16;
typedef unsigned long long u64;
typedef _Float16 h2 __attribute__((ext_vector_type(2)));
typedef _Float16 h4 __attribute__((ext_vector_type(4)));
typedef _Float16 h8 __attribute__((ext_vector_type(8)));
typedef float f4 __attribute__((ext_vector_type(4)));

#define ROWS 65536   // B*A
#define NB 1024
#define NA 64

__device__ __forceinline__ float dot4(float4 w, float4 x){
  return w.x*x.x + w.y*x.y + w.z*x.z + w.w*x.w;
}
__device__ __forceinline__ h2 u32_h2(u32 v){ union { u32 u; h2 h; } x; x.u = v; return x.h; }
__device__ __forceinline__ h2 pack_h2(float a, float b){ h2 r; r.x = (_Float16)a; r.y = (_Float16)b; return r; }
__device__ __forceinline__ h4 pack_h4(float4 v){
  h4 r; r.x=(_Float16)v.x; r.y=(_Float16)v.y; r.z=(_Float16)v.z; r.w=(_Float16)v.w; return r;
}
__device__ __forceinline__ h4 pack_h4_relu(float4 v){
  h4 r; r.x=(_Float16)fmaxf(v.x,0.f); r.y=(_Float16)fmaxf(v.y,0.f);
  r.z=(_Float16)fmaxf(v.z,0.f); r.w=(_Float16)fmaxf(v.w,0.f); return r;
}
// fast sigmoid/tanh on v_exp_f32 + v_rcp_f32 (~1 ulp each; threshold is 1.1e-2)
__device__ __forceinline__ float fsig(float z){
  float e = __builtin_amdgcn_exp2f(-1.44269504f * z);
  return __builtin_amdgcn_rcpf(1.0f + e);
}
__device__ __forceinline__ float ftanh(float z){
  float e = __builtin_amdgcn_exp2f(2.885390082f * z);
  return 1.0f - 2.0f * __builtin_amdgcn_rcpf(1.0f + e);
}
__device__ __forceinline__ h8 load8f(const float* p){
  float4 a = *(const float4*)p;
  float4 b = *(const float4*)(p + 4);
  h8 r;
  r[0] = (_Float16)a.x; r[1] = (_Float16)a.y; r[2] = (_Float16)a.z; r[3] = (_Float16)a.w;
  r[4] = (_Float16)b.x; r[5] = (_Float16)b.y; r[6] = (_Float16)b.z; r[7] = (_Float16)b.w;
  return r;
}

// ---------------- weight f16 pre-convert (actor_2 weights) ----------------
__global__ __launch_bounds__(256) void k_cvt(
    const float* __restrict__ a2w1, const float* __restrict__ a2w2,
    _Float16* __restrict__ w1h, _Float16* __restrict__ w2h)
{
  int i = blockIdx.x * 256 + threadIdx.x;
  if (i < 32768) w1h[i] = (_Float16)a2w1[i];
  if (i < 8192)  w2h[i] = (_Float16)a2w2[i];
}

// ---------------- actor_1 + attention: 8 rows per block, 128 threads ----------------
// kept f32/VALU: feeds the DISCRETE decisions (isinit threshold, K-nearest argsort) where
// f16 rounding (~1e-3) could flip group membership and blow up absmax.
__global__ __launch_bounds__(128) void k_actor1(
    const float* __restrict__ obs, const float* __restrict__ w1, const float* __restrict__ b1,
    const float* __restrict__ lng, const float* __restrict__ lnb,
    const float* __restrict__ w2, const float* __restrict__ b2,
    const float* __restrict__ aw1, const float* __restrict__ ab1,
    const float* __restrict__ aw2, const float* __restrict__ ab2,
    const float* __restrict__ aw3, const float* __restrict__ ab3,
    float* __restrict__ thoughts, int* __restrict__ isinit)
{
  const int b0 = blockIdx.x * 8;
  const int t = threadIdx.x;
  __shared__ float4 xs[8][64];     // 8 obs rows (256 f32 each)
  __shared__ float hs[8][128];     // relu(LN(h))
  __shared__ float tb[8][128];     // thoughts
  __shared__ float ab[8][64];
  __shared__ float a2b[8][64];
  __shared__ float red[8][4];

  { const float4* og = (const float4*)(obs + (size_t)b0 * 256);
    #pragma unroll
    for (int j = 0; j < 4; j++){ int p = j * 128 + t; xs[p >> 6][p & 63] = og[p]; } }
  __syncthreads();

  // h = obs @ W1^T + b1   (thread t owns output feature t, streams W1 row t)
  float acc[8];
  #pragma unroll
  for (int r = 0; r < 8; r++) acc[r] = b1[t];
  { const float4* wr = (const float4*)(w1 + (size_t)t * 256);
    for (int j = 0; j < 64; j++){
      float4 w = wr[j];
      #pragma unroll
      for (int r = 0; r < 8; r++) acc[r] += dot4(w, xs[r][j]);
    } }

  // LayerNorm over 128 features (block = 2 waves)
  #pragma unroll
  for (int r = 0; r < 8; r++){
    float s = acc[r], s2 = acc[r] * acc[r];
    #pragma unroll
    for (int off = 32; off > 0; off >>= 1){ s += __shfl_down(s, off); s2 += __shfl_down(s2, off); }
    if ((t & 63) == 0){ red[r][t >> 6] = s; red[r][2 + (t >> 6)] = s2; }
  }
  __syncthreads();
  const float g_ = lng[t], bb_ = lnb[t];
  #pragma unroll
  for (int r = 0; r < 8; r++){
    float mu  = (red[r][0] + red[r][1]) * (1.0f/128.0f);
    float var = (red[r][2] + red[r][3]) * (1.0f/128.0f) - mu * mu;
    hs[r][t] = fmaxf((acc[r] - mu) * rsqrtf(var + 1e-5f) * g_ + bb_, 0.0f);
  }
  __syncthreads();

  // thoughts = relu(h) @ W2^T + b2
  float acc2[8];
  #pragma unroll
  for (int r = 0; r < 8; r++) acc2[r] = b2[t];
  { const float4* wr = (const float4*)(w2 + (size_t)t * 128);
    for (int j = 0; j < 32; j++){
      float4 w = wr[j];
      #pragma unroll
      for (int r = 0; r < 8; r++) acc2[r] += dot4(w, ((const float4*)hs[r])[j]);
    } }
  #pragma unroll
  for (int r = 0; r < 8; r++){
    thoughts[(size_t)(b0 + r) * 128 + t] = acc2[r];
    tb[r][t] = acc2[r];
  }
  __syncthreads();

  // attention MLP
  if (t < 64){
    float a[8];
    #pragma unroll
    for (int r = 0; r < 8; r++) a[r] = ab1[t];
    const float4* wr = (const float4*)(aw1 + (size_t)t * 128);
    for (int j = 0; j < 32; j++){
      float4 w = wr[j];
      #pragma unroll
      for (int r = 0; r < 8; r++) a[r] += dot4(w, ((const float4*)tb[r])[j]);
    }
    #pragma unroll
    for (int r = 0; r < 8; r++) ab[r][t] = fmaxf(a[r], 0.0f);
  }
  __syncthreads();
  if (t < 64){
    float a[8];
    #pragma unroll
    for (int r = 0; r < 8; r++) a[r] = ab2[t];
    const float4* wr = (const float4*)(aw2 + (size_t)t * 64);
    for (int j = 0; j < 16; j++){
      float4 w = wr[j];
      #pragma unroll
      for (int r = 0; r < 8; r++) a[r] += dot4(w, ((const float4*)ab[r])[j]);
    }
    #pragma unroll
    for (int r = 0; r < 8; r++) a2b[r][t] = fmaxf(a[r], 0.0f);
  }
  __syncthreads();
  if (t < 8){
    float p = ab3[0];
    for (int j = 0; j < 64; j++) p += aw3[j] * a2b[t][j];
    isinit[b0 + t] = (p > 0.0f) ? 1 : 0;   // sigmoid(p) > 0.5  <=>  p > 0
  }
}

// ---------------- K-nearest groups: one block per batch ----------------
__global__ __launch_bounds__(256) void k_groups(
    const float* __restrict__ thoughts, int* __restrict__ idxout)
{
  const int b = blockIdx.x;
  const int tid = threadIdx.x;
  __shared__ float T[64 * 130];
  __shared__ float sq[64];
  for (int p = tid; p < 8192; p += 256){
    T[(p >> 7) * 130 + (p & 127)] = thoughts[(size_t)b * 8192 + p];
  }
  __syncthreads();
  if (tid < 64){
    const float2* tj = (const float2*)&T[tid * 130];
    float s = 0.0f;
    #pragma unroll 8
    for (int k = 0; k < 64; k++){ float2 v = tj[k]; s += v.x*v.x + v.y*v.y; }
    sq[tid] = s;
  }
  __syncthreads();
  const int lane = tid & 63;
  const int wv = tid >> 6;
  const float2* tj = (const float2*)&T[lane * 130];
  const float sqj = sq[lane];
  for (int ii = 0; ii < 16; ii++){
    const int i = wv * 16 + ii;
    const float2* ti = (const float2*)&T[i * 130];
    float dot = 0.0f;
    #pragma unroll 8
    for (int k = 0; k < 64; k++){ float2 a = ti[k]; float2 c = tj[k]; dot += a.x*c.x + a.y*c.y; }
    float d = fmaxf(sq[i] + sqj - 2.0f*dot, 0.0f);   // clamp keeps uint-compare == float-compare
    u64 key = (((u64)__float_as_uint(d)) << 32) | (u32)lane;
    u64 mask = 0;
    for (int q = 0; q < 8; q++){
      u64 m = key;
      #pragma unroll
      for (int off = 32; off > 0; off >>= 1){ u64 o = __shfl_xor(m, off); if (o < m) m = o; }
      mask |= 1ull << (u32)(m & 63u);
      if (key == m) key = ~0ull;
    }
    if (lane == 0){
      u64 mm = mask;
      int base = (b * 64 + i) * 8;
      #pragma unroll
      for (int q = 0; q < 8; q++){ int j = (int)__builtin_ctzll(mm); mm &= mm - 1; idxout[base + q] = j; }
    }
  }
}

// ---------------- sequential gather -> bi-LSTM -> scatter: FOUR batches per block ----------------
// v9 = v7 structure (best known: 403 us) with 4 batches per block. v7's round cost is
// interval-LATENCY-bound (~40 issue-cyc of work per ~2K-cyc interval), so amortize: the
// same 9 barrier intervals per round now serve 4 batches. Grid 256, 1 block/CU, LDS ~114KB.
//  * phase A: v7 wave roles (dir, wsub) x two batch-pairs; each pair uses the verified
//    2-batch A-row packing (rows 0-7 = even batch, 8-15 = odd batch). 32 MFMA/wave/round.
//  * phase B: wave (dir, l-slice=wsub) runs the verified step body for 4 batches; the 4
//    independent chains overlap inside one interval (ILP hides LDS/MFMA latency).
//  * rounds/block 48 -> 60 (P(any of 4 active) = 93.75%) but 2x batches/block and no
//    2-block CU contention -> net predicted ~35% gain.
// Abandoned branch: barrier-free single-wave recurrence (v6/v8) - measured latency-worse
// than the 8-wave + barrier structure (select-drain + bperm chain > barrier cost).
// MFMA conventions (verified v3-v8): A row = lane&15, B col = lane&15,
// k = kt*32 + (lane>>4)*8 + j, C: col = lane&15, row = (lane>>4)*4 + reg.
__global__ __launch_bounds__(512) void k_scan(
    const float* __restrict__ thoughts, const int* __restrict__ isinit, const int* __restrict__ idx,
    const float* __restrict__ wihf, const float* __restrict__ whhf,
    const float* __restrict__ bihf, const float* __restrict__ bhhf,
    const float* __restrict__ wihb, const float* __restrict__ whhb,
    const float* __restrict__ bihb, const float* __restrict__ bhhb,
    float* __restrict__ newt)
{
  const int b0   = blockIdx.x * 4;
  const int tid  = threadIdx.x;
  const int w    = tid >> 6;          // wave 0..7
  const int lane = tid & 63;
  const int dir  = w >> 2;            // waves 0-3 fwd, 4-7 bwd
  const int wsub = w & 3;             // phase-A gate == phase-B l-slice
  const int lr   = lane & 15;
  const int hi   = lane >> 4;

  __shared__ __align__(16) _Float16 nt16[4][64 * 136]; // f16 state mirrors (4 x 17408 B)
  __shared__ __align__(16) _Float16 Zx16[4][2*8*64*4]; // input projections (4 x 8192 B)
  __shared__ __align__(16) _Float16 hb16[4][2][64];    // h states
  __shared__ int gall[4][512];
  __shared__ int flags[4][64];
  __shared__ int dirty[4][64];

  const float* wih = dir ? wihb : wihf;
  const float* whh = dir ? whhb : whhf;

  // phase-A B fragments: Wih[(wsub*64 + ni*16 + lr)][kt*32 + hi*8 + j]  (64 VGPR)
  h8 Bf[4][4];
  #pragma unroll
  for (int ni = 0; ni < 4; ni++){
    const float* wr = wih + (size_t)((wsub << 6) + (ni << 4) + lr) * 128 + (hi << 3);
    #pragma unroll
    for (int kt = 0; kt < 4; kt++) Bf[ni][kt] = load8f(wr + kt * 32);
    __builtin_amdgcn_sched_barrier(0);   // cap init liveness
  }
  // phase-B B fragments: Whh[(gg*64 + wsub*16 + lr)][kt*32 + hi*8 + j]  (32 VGPR)
  h8 Bh[4][2];
  #pragma unroll
  for (int gg = 0; gg < 4; gg++){
    const float* wr = whh + (size_t)((gg << 6) + (wsub << 4) + lr) * 64 + (hi << 3);
    #pragma unroll
    for (int kt = 0; kt < 2; kt++) Bh[gg][kt] = load8f(wr + kt * 32);
    __builtin_amdgcn_sched_barrier(0);
  }
  // bias for the Zx columns this lane writes (batch-independent)
  float biasl[4];
  {
    const float* bih = dir ? bihb : bihf;
    const float* bhh = dir ? bhhb : bhhf;
    #pragma unroll
    for (int ni = 0; ni < 4; ni++){
      int n = (wsub << 6) + (ni << 4) + lr;
      biasl[ni] = bih[n] + bhh[n];
    }
  }

  #pragma unroll
  for (int q = 0; q < 4; q++){
    const float4* tf4 = (const float4*)(thoughts + (size_t)(b0 + q) * 8192);
    #pragma unroll
    for (int k2 = 0; k2 < 4; k2++){
      int id4 = tid + k2 * 512;                 // f4 index, 2048 per batch (32 f4 per row)
      float4 v = tf4[id4];
      *(h4*)&nt16[q][(id4 >> 5) * 136 + (id4 & 31) * 4] = pack_h4(v);
    }
  }
  #pragma unroll
  for (int k2 = 0; k2 < 4; k2++){
    int p = tid + k2 * 512;
    gall[p >> 9][p & 511] = idx[(size_t)b0 * 512 + p];
  }
  if (tid < 256){ int q = tid >> 6, j = tid & 63;
    flags[q][j] = isinit[(b0 + q) * 64 + j]; dirty[q][j] = 0; }
  __syncthreads();

  #pragma unroll 1
  for (int i = 0; i < 64; i++){
    const int f0 = flags[0][i], f1 = flags[1][i], f2 = flags[2][i], f3 = flags[3][i];
    if (!(f0 | f1 | f2 | f3)) continue;           // block-uniform
    if (tid < 32){ int q = tid >> 3, j = tid & 7;
      int fq = (q == 0) ? f0 : (q == 1) ? f1 : (q == 2) ? f2 : f3;
      if (fq) dirty[q][gall[q][i * 8 + j]] = 1; }

    // ---- phase A: two batch-pairs, each with 2-batch A-row packing (rows 0-7/8-15) ----
    #pragma unroll
    for (int pr = 0; pr < 2; pr++){
      const int fp = pr ? (f2 | f3) : (f0 | f1);
      if (fp){
        const int qa = (pr << 1) + (lr >> 3);
        const int grow = gall[qa][i * 8 + (lr & 7)];
        h8 Af[4];
        #pragma unroll
        for (int kt = 0; kt < 4; kt++)
          Af[kt] = *(const h8*)&nt16[qa][grow * 136 + kt * 32 + (hi << 3)];
        const int qo = (pr << 1) + (hi >> 1), t0 = (hi & 1) << 2;
        #pragma unroll
        for (int ni = 0; ni < 4; ni++){
          f4 acc = {0.0f, 0.0f, 0.0f, 0.0f};
          #pragma unroll
          for (int kt = 0; kt < 4; kt++)
            acc = __builtin_amdgcn_mfma_f32_16x16x32_f16(Af[kt], Bf[ni][kt], acc, 0, 0, 0);
          const int lp = (ni << 4) + lr;
          #pragma unroll
          for (int r = 0; r < 4; r++)
            Zx16[qo][(((dir << 3) + t0 + r) * 64 + lp) * 4 + wsub] = (_Float16)(acc[r] + biasl[ni]);
        }
      }
    }
    __syncthreads();

    // ---- phase B: 8 steps; wave (dir, l-slice) serves all 4 batches (same Bh) ----
    float c0 = 0.0f, c1 = 0.0f, c2 = 0.0f, c3 = 0.0f;
    #pragma unroll
    for (int s = 0; s < 8; s++){
      const int tt = dir ? (7 - s) : s;
      #pragma unroll
      for (int q = 0; q < 4; q++){
        const int fq = (q == 0) ? f0 : (q == 1) ? f1 : (q == 2) ? f2 : f3;
        if (!fq) continue;   // block-uniform
        uint2 zr = *(const uint2*)&Zx16[q][(((dir << 3) + tt) * 64 + (wsub << 4) + lr) * 4];
        h2 zlo = u32_h2(zr.x), zhi2 = u32_h2(zr.y);
        float z0 = (float)zlo.x, z1 = (float)zlo.y, z2 = (float)zhi2.x, z3 = (float)zhi2.y;
        if (s > 0){
          h8 a0 = *(const h8*)&hb16[q][dir][(hi << 3)];
          h8 a1 = *(const h8*)&hb16[q][dir][32 + (hi << 3)];
          f4 A;
          A = (f4){z0, 0.f, 0.f, 0.f};
          A = __builtin_amdgcn_mfma_f32_16x16x32_f16(a0, Bh[0][0], A, 0, 0, 0);
          A = __builtin_amdgcn_mfma_f32_16x16x32_f16(a1, Bh[0][1], A, 0, 0, 0);
          z0 = A[0];
          A = (f4){z1, 0.f, 0.f, 0.f};
          A = __builtin_amdgcn_mfma_f32_16x16x32_f16(a0, Bh[1][0], A, 0, 0, 0);
          A = __builtin_amdgcn_mfma_f32_16x16x32_f16(a1, Bh[1][1], A, 0, 0, 0);
          z1 = A[0];
          A = (f4){z2, 0.f, 0.f, 0.f};
          A = __builtin_amdgcn_mfma_f32_16x16x32_f16(a0, Bh[2][0], A, 0, 0, 0);
          A = __builtin_amdgcn_mfma_f32_16x16x32_f16(a1, Bh[2][1], A, 0, 0, 0);
          z2 = A[0];
          A = (f4){z3, 0.f, 0.f, 0.f};
          A = __builtin_amdgcn_mfma_f32_16x16x32_f16(a0, Bh[3][0], A, 0, 0, 0);
          A = __builtin_amdgcn_mfma_f32_16x16x32_f16(a1, Bh[3][1], A, 0, 0, 0);
          z3 = A[0];
        }
        float fi = fsig(z0);
        float ff = fsig(z1);
        float fg = ftanh(z2);
        float fo = fsig(z3);
        float cc = (q == 0) ? c0 : (q == 1) ? c1 : (q == 2) ? c2 : c3;
        cc = ff * cc + fi * fg;
        if (q == 0) c0 = cc; else if (q == 1) c1 = cc; else if (q == 2) c2 = cc; else c3 = cc;
        float hn = fo * ftanh(cc);
        if (hi == 0){
          hb16[q][dir][(wsub << 4) + lr] = (_Float16)hn;
          nt16[q][gall[q][i * 8 + tt] * 136 + (dir << 6) + (wsub << 4) + lr] = (_Float16)hn;
        }
      }
      __syncthreads();
    }
  }

  __syncthreads();
  #pragma unroll
  for (int q = 0; q < 4; q++){
    const float4* tf4 = (const float4*)(thoughts + (size_t)(b0 + q) * 8192);
    float4* of4 = (float4*)(newt + (size_t)(b0 + q) * 8192);
    #pragma unroll
    for (int k2 = 0; k2 < 4; k2++){
      int id4 = tid + k2 * 512;
      int row = id4 >> 5, c4 = (id4 & 31) * 4;
      float4 v = tf4[id4];
      if (dirty[q][row]){
        h4 hv = *(const h4*)&nt16[q][row * 136 + c4];
        v.x = (float)hv.x; v.y = (float)hv.y; v.z = (float)hv.z; v.w = (float)hv.w;
      }
      of4[id4] = v;
    }
  }
}

// ---------------- actor_2 (MFMA f16): 32 rows per block, 256 threads ----------------
// x = relu(concat(thoughts,newt)) (32x256) @ a2w1^T (256->128) + b1 -> (32x128) @ a2w2^T
// (128->64) -> tanh. f16 inputs/weights, f32 accum; no discrete decisions downstream.
__global__ __launch_bounds__(256) void k_actor2(
    const float* __restrict__ thoughts, const float* __restrict__ newt,
    const _Float16* __restrict__ w1h, const float* __restrict__ b1,
    const _Float16* __restrict__ w2h, float* __restrict__ out)
{
  const int b0 = blockIdx.x * 32;
  const int tid = threadIdx.x;
  const int w = tid >> 6, lane = tid & 63, lr = lane & 15, hi = lane >> 4;
  const int mt = w & 1, nb = (w >> 1) << 6;

  __shared__ __align__(16) _Float16 Xc[32 * 264];   // relu(concat) f16, padded (16896 B)
  __shared__ __align__(16) _Float16 Ys[32 * 136];   // hidden f16, padded (8704 B)

  #pragma unroll
  for (int k2 = 0; k2 < 8; k2++){
    int id4 = tid + k2 * 256;              // f4 index over 32 rows x 64 f4
    int row = id4 >> 6, c4 = (id4 & 63) * 4;
    const float* src = (c4 < 128) ? (thoughts + (size_t)(b0 + row) * 128 + c4)
                                  : (newt + (size_t)(b0 + row) * 128 + (c4 - 128));
    float4 v = *(const float4*)src;
    *(h4*)&Xc[row * 264 + c4] = pack_h4_relu(v);
  }
  __syncthreads();

  // GEMM1: wave (mt, nb): rows mt*16.., cols nb..nb+63
  {
    h8 Af[8];
    #pragma unroll
    for (int kt = 0; kt < 8; kt++)
      Af[kt] = *(const h8*)&Xc[(mt * 16 + lr) * 264 + kt * 32 + (hi << 3)];
    #pragma unroll
    for (int ni = 0; ni < 4; ni++){
      const int n = nb + ni * 16 + lr;
      const _Float16* wr = w1h + (size_t)n * 256 + (hi << 3);
      f4 acc = {0.0f, 0.0f, 0.0f, 0.0f};
      #pragma unroll
      for (int kt = 0; kt < 8; kt++){
        h8 bfr = *(const h8*)(wr + kt * 32);
        acc = __builtin_amdgcn_mfma_f32_16x16x32_f16(Af[kt], bfr, acc, 0, 0, 0);
      }
      const float bb = b1[n];
      #pragma unroll
      for (int r = 0; r < 4; r++){
        int row = mt * 16 + (hi << 2) + r;
        Ys[row * 136 + n] = (_Float16)(acc[r] + bb);
      }
    }
  }
  __syncthreads();

  // GEMM2: wave (mt, ni0): rows mt*16.., cols (ni0..ni0+1)*16
  {
    const int ni0 = (w >> 1) << 1;
    h8 Ag[4];
    #pragma unroll
    for (int kt = 0; kt < 4; kt++)
      Ag[kt] = *(const h8*)&Ys[(mt * 16 + lr) * 136 + kt * 32 + (hi << 3)];
    #pragma unroll
    for (int nj = 0; nj < 2; nj++){
      const int n = (ni0 + nj) * 16 + lr;
      const _Float16* wr = w2h + (size_t)n * 128 + (hi << 3);
      f4 acc = {0.0f, 0.0f, 0.0f, 0.0f};
      #pragma unroll
      for (int kt = 0; kt < 4; kt++){
        h8 bfr = *(const h8*)(wr + kt * 32);
        acc = __builtin_amdgcn_mfma_f32_16x16x32_f16(Ag[kt], bfr, acc, 0, 0, 0);
      }
      #pragma unroll
      for (int r = 0; r < 4; r++){
        int row = mt * 16 + (hi << 2) + r;
        out[(size_t)(b0 + row) * 64 + n] = ftanh(acc[r]);
      }
    }
  }
}

extern "C" void kernel_launch(void* const* d_in, const int* in_sizes, int n_in,
                              void* d_out, int out_size, void* d_ws, size_t ws_size,
                              hipStream_t stream)
{
  const float* obs  = (const float*)d_in[0];
  const float* w1   = (const float*)d_in[1];
  const float* b1   = (const float*)d_in[2];
  const float* lng  = (const float*)d_in[3];
  const float* lnb  = (const float*)d_in[4];
  const float* w2   = (const float*)d_in[5];
  const float* b2   = (const float*)d_in[6];
  const float* aw1  = (const float*)d_in[7];
  const float* ab1  = (const float*)d_in[8];
  const float* aw2  = (const float*)d_in[9];
  const float* ab2  = (const float*)d_in[10];
  const float* aw3  = (const float*)d_in[11];
  const float* ab3  = (const float*)d_in[12];
  const float* wihf = (const float*)d_in[13];
  const float* whhf = (const float*)d_in[14];
  const float* bihf = (const float*)d_in[15];
  const float* bhhf = (const float*)d_in[16];
  const float* wihb = (const float*)d_in[17];
  const float* whhb = (const float*)d_in[18];
  const float* bihb = (const float*)d_in[19];
  const float* bhhb = (const float*)d_in[20];
  const float* a2w1 = (const float*)d_in[21];
  const float* a2b1 = (const float*)d_in[22];
  const float* a2w2 = (const float*)d_in[23];

  float* thoughts = (float*)d_ws;                       // 33.5 MB
  float* newt     = thoughts + (size_t)ROWS * 128;      // 33.5 MB
  int*   isinit   = (int*)(newt + (size_t)ROWS * 128);  // 256 KB
  int*   idxb     = isinit + ROWS;                      // 2 MB
  _Float16* w1h   = (_Float16*)(idxb + (size_t)ROWS * 8);  // 64 KB
  _Float16* w2h   = w1h + 32768;                           // 16 KB

  hipLaunchKernelGGL(k_cvt, dim3(128), dim3(256), 0, stream, a2w1, a2w2, w1h, w2h);
  hipLaunchKernelGGL(k_actor1, dim3(ROWS / 8), dim3(128), 0, stream,
                     obs, w1, b1, lng, lnb, w2, b2, aw1, ab1, aw2, ab2, aw3, ab3,
                     thoughts, isinit);
  hipLaunchKernelGGL(k_groups, dim3(NB), dim3(256), 0, stream, thoughts, idxb);
  hipLaunchKernelGGL(k_scan, dim3(NB / 4), dim3(512), 0, stream,
                     thoughts, isinit, idxb,
                     wihf, whhf, bihf, bhhf, wihb, whhb, bihb, bhhb, newt);
  hipLaunchKernelGGL(k_actor2, dim3(ROWS / 32), dim3(256), 0, stream,
                     thoughts, newt, w1h, a2b1, w2h, (float*)d_out);
}

// Round 9
// 909.938 us; speedup vs baseline: 1.1413x; 1.0149x over previous
//
#include <hip/hip_runtime.h>

typedef unsigned int u32;
typedef unsigned short u16;
typedef unsigned long long u64;
typedef _Float16 h2 __attribute__((ext_vector_type(2)));
typedef _Float16 h4 __attribute__((ext_vector_type(4)));
typedef _Float16 h8 __attribute__((ext_vector_type(8)));
typedef float f4 __attribute__((ext_vector_type(4)));

#define ROWS 65536   // B*A
#define NB 1024
#define NA 64

__device__ __forceinline__ float dot4(float4 w, float4 x){
  return w.x*x.x + w.y*x.y + w.z*x.z + w.w*x.w;
}
__device__ __forceinline__ h2 u32_h2(u32 v){ union { u32 u; h2 h; } x; x.u = v; return x.h; }
__device__ __forceinline__ h2 pack_h2(float a, float b){ h2 r; r.x = (_Float16)a; r.y = (_Float16)b; return r; }
__device__ __forceinline__ h4 pack_h4(float4 v){
  h4 r; r.x=(_Float16)v.x; r.y=(_Float16)v.y; r.z=(_Float16)v.z; r.w=(_Float16)v.w; return r;
}
__device__ __forceinline__ h4 pack_h4_relu(float4 v){
  h4 r; r.x=(_Float16)fmaxf(v.x,0.f); r.y=(_Float16)fmaxf(v.y,0.f);
  r.z=(_Float16)fmaxf(v.z,0.f); r.w=(_Float16)fmaxf(v.w,0.f); return r;
}
// fast sigmoid/tanh on v_exp_f32 + v_rcp_f32 (~1 ulp each; threshold is 1.1e-2)
__device__ __forceinline__ float fsig(float z){
  float e = __builtin_amdgcn_exp2f(-1.44269504f * z);
  return __builtin_amdgcn_rcpf(1.0f + e);
}
__device__ __forceinline__ float ftanh(float z){
  float e = __builtin_amdgcn_exp2f(2.885390082f * z);
  return 1.0f - 2.0f * __builtin_amdgcn_rcpf(1.0f + e);
}
__device__ __forceinline__ h8 load8f(const float* p){
  float4 a = *(const float4*)p;
  float4 b = *(const float4*)(p + 4);
  h8 r;
  r[0] = (_Float16)a.x; r[1] = (_Float16)a.y; r[2] = (_Float16)a.z; r[3] = (_Float16)a.w;
  r[4] = (_Float16)b.x; r[5] = (_Float16)b.y; r[6] = (_Float16)b.z; r[7] = (_Float16)b.w;
  return r;
}

// ---------------- weight f16 pre-convert (actor_2 weights) ----------------
__global__ __launch_bounds__(256) void k_cvt(
    const float* __restrict__ a2w1, const float* __restrict__ a2w2,
    _Float16* __restrict__ w1h, _Float16* __restrict__ w2h)
{
  int i = blockIdx.x * 256 + threadIdx.x;
  if (i < 32768) w1h[i] = (_Float16)a2w1[i];
  if (i < 8192)  w2h[i] = (_Float16)a2w2[i];
}

// ---------------- actor_1 + attention: 8 rows per block, 128 threads ----------------
// kept f32/VALU: feeds the DISCRETE decisions (isinit threshold, K-nearest argsort) where
// f16 rounding (~1e-3) could flip group membership and blow up absmax.
__global__ __launch_bounds__(128) void k_actor1(
    const float* __restrict__ obs, const float* __restrict__ w1, const float* __restrict__ b1,
    const float* __restrict__ lng, const float* __restrict__ lnb,
    const float* __restrict__ w2, const float* __restrict__ b2,
    const float* __restrict__ aw1, const float* __restrict__ ab1,
    const float* __restrict__ aw2, const float* __restrict__ ab2,
    const float* __restrict__ aw3, const float* __restrict__ ab3,
    float* __restrict__ thoughts, int* __restrict__ isinit)
{
  const int b0 = blockIdx.x * 8;
  const int t = threadIdx.x;
  __shared__ float4 xs[8][64];     // 8 obs rows (256 f32 each)
  __shared__ float hs[8][128];     // relu(LN(h))
  __shared__ float tb[8][128];     // thoughts
  __shared__ float ab[8][64];
  __shared__ float a2b[8][64];
  __shared__ float red[8][4];

  { const float4* og = (const float4*)(obs + (size_t)b0 * 256);
    #pragma unroll
    for (int j = 0; j < 4; j++){ int p = j * 128 + t; xs[p >> 6][p & 63] = og[p]; } }
  __syncthreads();

  // h = obs @ W1^T + b1   (thread t owns output feature t, streams W1 row t)
  float acc[8];
  #pragma unroll
  for (int r = 0; r < 8; r++) acc[r] = b1[t];
  { const float4* wr = (const float4*)(w1 + (size_t)t * 256);
    for (int j = 0; j < 64; j++){
      float4 w = wr[j];
      #pragma unroll
      for (int r = 0; r < 8; r++) acc[r] += dot4(w, xs[r][j]);
    } }

  // LayerNorm over 128 features (block = 2 waves)
  #pragma unroll
  for (int r = 0; r < 8; r++){
    float s = acc[r], s2 = acc[r] * acc[r];
    #pragma unroll
    for (int off = 32; off > 0; off >>= 1){ s += __shfl_down(s, off); s2 += __shfl_down(s2, off); }
    if ((t & 63) == 0){ red[r][t >> 6] = s; red[r][2 + (t >> 6)] = s2; }
  }
  __syncthreads();
  const float g_ = lng[t], bb_ = lnb[t];
  #pragma unroll
  for (int r = 0; r < 8; r++){
    float mu  = (red[r][0] + red[r][1]) * (1.0f/128.0f);
    float var = (red[r][2] + red[r][3]) * (1.0f/128.0f) - mu * mu;
    hs[r][t] = fmaxf((acc[r] - mu) * rsqrtf(var + 1e-5f) * g_ + bb_, 0.0f);
  }
  __syncthreads();

  // thoughts = relu(h) @ W2^T + b2
  float acc2[8];
  #pragma unroll
  for (int r = 0; r < 8; r++) acc2[r] = b2[t];
  { const float4* wr = (const float4*)(w2 + (size_t)t * 128);
    for (int j = 0; j < 32; j++){
      float4 w = wr[j];
      #pragma unroll
      for (int r = 0; r < 8; r++) acc2[r] += dot4(w, ((const float4*)hs[r])[j]);
    } }
  #pragma unroll
  for (int r = 0; r < 8; r++){
    thoughts[(size_t)(b0 + r) * 128 + t] = acc2[r];
    tb[r][t] = acc2[r];
  }
  __syncthreads();

  // attention MLP
  if (t < 64){
    float a[8];
    #pragma unroll
    for (int r = 0; r < 8; r++) a[r] = ab1[t];
    const float4* wr = (const float4*)(aw1 + (size_t)t * 128);
    for (int j = 0; j < 32; j++){
      float4 w = wr[j];
      #pragma unroll
      for (int r = 0; r < 8; r++) a[r] += dot4(w, ((const float4*)tb[r])[j]);
    }
    #pragma unroll
    for (int r = 0; r < 8; r++) ab[r][t] = fmaxf(a[r], 0.0f);
  }
  __syncthreads();
  if (t < 64){
    float a[8];
    #pragma unroll
    for (int r = 0; r < 8; r++) a[r] = ab2[t];
    const float4* wr = (const float4*)(aw2 + (size_t)t * 64);
    for (int j = 0; j < 16; j++){
      float4 w = wr[j];
      #pragma unroll
      for (int r = 0; r < 8; r++) a[r] += dot4(w, ((const float4*)ab[r])[j]);
    }
    #pragma unroll
    for (int r = 0; r < 8; r++) a2b[r][t] = fmaxf(a[r], 0.0f);
  }
  __syncthreads();
  if (t < 8){
    float p = ab3[0];
    for (int j = 0; j < 64; j++) p += aw3[j] * a2b[t][j];
    isinit[b0 + t] = (p > 0.0f) ? 1 : 0;   // sigmoid(p) > 0.5  <=>  p > 0
  }
}

// ---------------- K-nearest groups: one block per batch ----------------
__global__ __launch_bounds__(256) void k_groups(
    const float* __restrict__ thoughts, int* __restrict__ idxout)
{
  const int b = blockIdx.x;
  const int tid = threadIdx.x;
  __shared__ float T[64 * 130];
  __shared__ float sq[64];
  for (int p = tid; p < 8192; p += 256){
    T[(p >> 7) * 130 + (p & 127)] = thoughts[(size_t)b * 8192 + p];
  }
  __syncthreads();
  if (tid < 64){
    const float2* tj = (const float2*)&T[tid * 130];
    float s = 0.0f;
    #pragma unroll 8
    for (int k = 0; k < 64; k++){ float2 v = tj[k]; s += v.x*v.x + v.y*v.y; }
    sq[tid] = s;
  }
  __syncthreads();
  const int lane = tid & 63;
  const int wv = tid >> 6;
  const float2* tj = (const float2*)&T[lane * 130];
  const float sqj = sq[lane];
  for (int ii = 0; ii < 16; ii++){
    const int i = wv * 16 + ii;
    const float2* ti = (const float2*)&T[i * 130];
    float dot = 0.0f;
    #pragma unroll 8
    for (int k = 0; k < 64; k++){ float2 a = ti[k]; float2 c = tj[k]; dot += a.x*c.x + a.y*c.y; }
    float d = fmaxf(sq[i] + sqj - 2.0f*dot, 0.0f);   // clamp keeps uint-compare == float-compare
    u64 key = (((u64)__float_as_uint(d)) << 32) | (u32)lane;
    u64 mask = 0;
    for (int q = 0; q < 8; q++){
      u64 m = key;
      #pragma unroll
      for (int off = 32; off > 0; off >>= 1){ u64 o = __shfl_xor(m, off); if (o < m) m = o; }
      mask |= 1ull << (u32)(m & 63u);
      if (key == m) key = ~0ull;
    }
    if (lane == 0){
      u64 mm = mask;
      int base = (b * 64 + i) * 8;
      #pragma unroll
      for (int q = 0; q < 8; q++){ int j = (int)__builtin_ctzll(mm); mm &= mm - 1; idxout[base + q] = j; }
    }
  }
}

// ---------------- sequential gather -> bi-LSTM -> scatter: FOUR batches per block ----------------
// v10 = v9 with the phase-B recurrence matvec 4-BATCH-PACKED into the MFMA rows:
// A row r carries batch (r&3)'s h (each lane loads hb16[lr&3], rows 0-15 = batches 0123
// repeating); C reg r is initialized with batch r's Zx. Then C[row=4h+r][col=lr] = batch r's
// z -> EVERY lane's reg r = batch r's z for its l (correct redundancy across hi groups, same
// as v9's dup-trick). 8 MFMA/step/wave (was 32): phase-B matrix-pipe issue drops 4x (the
// measured v9 bound: 64 MFMA x ~19 SIMD-cyc ~= the 1.7K-cyc step interval). z math is
// bitwise identical (same chained-MFMA K-accumulation) -> absmax unchanged.
// hb16 padded [4][2][72] (q-stride 288 B = 8-bank skew; residual 2-way conflicts free) and
// zero-initialized (inactive batches feed finite stale A rows; their C rows are discarded).
// LDS 113 KB already forces 1 block/CU, so __launch_bounds__(512,2) raises the VGPR cap to
// 256 for free (headroom for the 4 live f4 accumulators; spill tripwire = WRITE_SIZE).
// MFMA conventions (verified v3-v9): A row = lane&15, B col = lane&15,
// k = kt*32 + (lane>>4)*8 + j, C: col = lane&15, row = (lane>>4)*4 + reg.
__global__ __launch_bounds__(512, 2) void k_scan(
    const float* __restrict__ thoughts, const int* __restrict__ isinit, const int* __restrict__ idx,
    const float* __restrict__ wihf, const float* __restrict__ whhf,
    const float* __restrict__ bihf, const float* __restrict__ bhhf,
    const float* __restrict__ wihb, const float* __restrict__ whhb,
    const float* __restrict__ bihb, const float* __restrict__ bhhb,
    float* __restrict__ newt)
{
  const int b0   = blockIdx.x * 4;
  const int tid  = threadIdx.x;
  const int w    = tid >> 6;          // wave 0..7
  const int lane = tid & 63;
  const int dir  = w >> 2;            // waves 0-3 fwd, 4-7 bwd
  const int wsub = w & 3;             // phase-A gate == phase-B l-slice
  const int lr   = lane & 15;
  const int hi   = lane >> 4;

  __shared__ __align__(16) _Float16 nt16[4][64 * 136]; // f16 state mirrors (4 x 17408 B)
  __shared__ __align__(16) _Float16 Zx16[4][2*8*64*4]; // input projections (4 x 8192 B)
  __shared__ __align__(16) _Float16 hb16[4][2][72];    // h states, 8-bank q-skew (1152 B)
  __shared__ int gall[4][512];
  __shared__ int flags[4][64];
  __shared__ int dirty[4][64];

  const float* wih = dir ? wihb : wihf;
  const float* whh = dir ? whhb : whhf;

  // phase-A B fragments: Wih[(wsub*64 + ni*16 + lr)][kt*32 + hi*8 + j]  (64 VGPR)
  h8 Bf[4][4];
  #pragma unroll
  for (int ni = 0; ni < 4; ni++){
    const float* wr = wih + (size_t)((wsub << 6) + (ni << 4) + lr) * 128 + (hi << 3);
    #pragma unroll
    for (int kt = 0; kt < 4; kt++) Bf[ni][kt] = load8f(wr + kt * 32);
    __builtin_amdgcn_sched_barrier(0);   // cap init liveness
  }
  // phase-B B fragments: Whh[(gg*64 + wsub*16 + lr)][kt*32 + hi*8 + j]  (32 VGPR)
  h8 Bh[4][2];
  #pragma unroll
  for (int gg = 0; gg < 4; gg++){
    const float* wr = whh + (size_t)((gg << 6) + (wsub << 4) + lr) * 64 + (hi << 3);
    #pragma unroll
    for (int kt = 0; kt < 2; kt++) Bh[gg][kt] = load8f(wr + kt * 32);
    __builtin_amdgcn_sched_barrier(0);
  }
  // bias for the Zx columns this lane writes (batch-independent)
  float biasl[4];
  {
    const float* bih = dir ? bihb : bihf;
    const float* bhh = dir ? bhhb : bhhf;
    #pragma unroll
    for (int ni = 0; ni < 4; ni++){
      int n = (wsub << 6) + (ni << 4) + lr;
      biasl[ni] = bih[n] + bhh[n];
    }
  }

  #pragma unroll
  for (int q = 0; q < 4; q++){
    const float4* tf4 = (const float4*)(thoughts + (size_t)(b0 + q) * 8192);
    #pragma unroll
    for (int k2 = 0; k2 < 4; k2++){
      int id4 = tid + k2 * 512;                 // f4 index, 2048 per batch (32 f4 per row)
      float4 v = tf4[id4];
      *(h4*)&nt16[q][(id4 >> 5) * 136 + (id4 & 31) * 4] = pack_h4(v);
    }
  }
  #pragma unroll
  for (int k2 = 0; k2 < 4; k2++){
    int p = tid + k2 * 512;
    gall[p >> 9][p & 511] = idx[(size_t)b0 * 512 + p];
  }
  if (tid < 256){ int q = tid >> 6, j = tid & 63;
    flags[q][j] = isinit[(b0 + q) * 64 + j]; dirty[q][j] = 0; }
  if (tid < 288) ((h2*)hb16)[tid] = pack_h2(0.0f, 0.0f);   // zero h states (576 f16)
  __syncthreads();

  #pragma unroll 1
  for (int i = 0; i < 64; i++){
    const int f0 = flags[0][i], f1 = flags[1][i], f2 = flags[2][i], f3 = flags[3][i];
    if (!(f0 | f1 | f2 | f3)) continue;           // block-uniform
    if (tid < 32){ int q = tid >> 3, j = tid & 7;
      int fq = (q == 0) ? f0 : (q == 1) ? f1 : (q == 2) ? f2 : f3;
      if (fq) dirty[q][gall[q][i * 8 + j]] = 1; }

    // ---- phase A: two batch-pairs, each with 2-batch A-row packing (rows 0-7/8-15) ----
    #pragma unroll
    for (int pr = 0; pr < 2; pr++){
      const int fp = pr ? (f2 | f3) : (f0 | f1);
      if (fp){
        const int qa = (pr << 1) + (lr >> 3);
        const int grow = gall[qa][i * 8 + (lr & 7)];
        h8 Af[4];
        #pragma unroll
        for (int kt = 0; kt < 4; kt++)
          Af[kt] = *(const h8*)&nt16[qa][grow * 136 + kt * 32 + (hi << 3)];
        const int qo = (pr << 1) + (hi >> 1), t0 = (hi & 1) << 2;
        #pragma unroll
        for (int ni = 0; ni < 4; ni++){
          f4 acc = {0.0f, 0.0f, 0.0f, 0.0f};
          #pragma unroll
          for (int kt = 0; kt < 4; kt++)
            acc = __builtin_amdgcn_mfma_f32_16x16x32_f16(Af[kt], Bf[ni][kt], acc, 0, 0, 0);
          const int lp = (ni << 4) + lr;
          #pragma unroll
          for (int r = 0; r < 4; r++)
            Zx16[qo][(((dir << 3) + t0 + r) * 64 + lp) * 4 + wsub] = (_Float16)(acc[r] + biasl[ni]);
        }
      }
    }
    __syncthreads();

    // ---- phase B: 8 steps; ONE packed MFMA set serves all 4 batches ----
    float c0 = 0.0f, c1 = 0.0f, c2 = 0.0f, c3 = 0.0f;
    #pragma unroll
    for (int s = 0; s < 8; s++){
      const int tt = dir ? (7 - s) : s;
      const int zoff = (((dir << 3) + tt) * 64 + (wsub << 4) + lr) * 4;
      uint2 zr0 = {0u,0u}, zr1 = {0u,0u}, zr2 = {0u,0u}, zr3 = {0u,0u};
      if (f0) zr0 = *(const uint2*)&Zx16[0][zoff];
      if (f1) zr1 = *(const uint2*)&Zx16[1][zoff];
      if (f2) zr2 = *(const uint2*)&Zx16[2][zoff];
      if (f3) zr3 = *(const uint2*)&Zx16[3][zoff];
      // C-init: reg r = batch r's Zx for this lane's l (gates i,f,g,o -> A0..A3)
      f4 A0, A1, A2, A3;
      { h2 pa = u32_h2(zr0.x), pb = u32_h2(zr0.y);
        A0[0] = (float)pa.x; A1[0] = (float)pa.y; A2[0] = (float)pb.x; A3[0] = (float)pb.y; }
      { h2 pa = u32_h2(zr1.x), pb = u32_h2(zr1.y);
        A0[1] = (float)pa.x; A1[1] = (float)pa.y; A2[1] = (float)pb.x; A3[1] = (float)pb.y; }
      { h2 pa = u32_h2(zr2.x), pb = u32_h2(zr2.y);
        A0[2] = (float)pa.x; A1[2] = (float)pa.y; A2[2] = (float)pb.x; A3[2] = (float)pb.y; }
      { h2 pa = u32_h2(zr3.x), pb = u32_h2(zr3.y);
        A0[3] = (float)pa.x; A1[3] = (float)pa.y; A2[3] = (float)pb.x; A3[3] = (float)pb.y; }
      if (s > 0){
        // A row r = batch (r&3)'s h: lane supplies row lr -> batch lr&3, k-slice hi*8+j
        const int qa = lr & 3;
        h8 a0 = *(const h8*)&hb16[qa][dir][(hi << 3)];
        h8 a1 = *(const h8*)&hb16[qa][dir][32 + (hi << 3)];
        A0 = __builtin_amdgcn_mfma_f32_16x16x32_f16(a0, Bh[0][0], A0, 0, 0, 0);
        A0 = __builtin_amdgcn_mfma_f32_16x16x32_f16(a1, Bh[0][1], A0, 0, 0, 0);
        A1 = __builtin_amdgcn_mfma_f32_16x16x32_f16(a0, Bh[1][0], A1, 0, 0, 0);
        A1 = __builtin_amdgcn_mfma_f32_16x16x32_f16(a1, Bh[1][1], A1, 0, 0, 0);
        A2 = __builtin_amdgcn_mfma_f32_16x16x32_f16(a0, Bh[2][0], A2, 0, 0, 0);
        A2 = __builtin_amdgcn_mfma_f32_16x16x32_f16(a1, Bh[2][1], A2, 0, 0, 0);
        A3 = __builtin_amdgcn_mfma_f32_16x16x32_f16(a0, Bh[3][0], A3, 0, 0, 0);
        A3 = __builtin_amdgcn_mfma_f32_16x16x32_f16(a1, Bh[3][1], A3, 0, 0, 0);
      }
      #pragma unroll
      for (int q = 0; q < 4; q++){
        const int fq = (q == 0) ? f0 : (q == 1) ? f1 : (q == 2) ? f2 : f3;
        if (!fq) continue;   // block-uniform
        float z0 = A0[q], z1 = A1[q], z2 = A2[q], z3 = A3[q];
        float fi = fsig(z0);
        float ff = fsig(z1);
        float fg = ftanh(z2);
        float fo = fsig(z3);
        float cc = (q == 0) ? c0 : (q == 1) ? c1 : (q == 2) ? c2 : c3;
        cc = ff * cc + fi * fg;
        if (q == 0) c0 = cc; else if (q == 1) c1 = cc; else if (q == 2) c2 = cc; else c3 = cc;
        float hn = fo * ftanh(cc);
        if (hi == 0){
          hb16[q][dir][(wsub << 4) + lr] = (_Float16)hn;
          nt16[q][gall[q][i * 8 + tt] * 136 + (dir << 6) + (wsub << 4) + lr] = (_Float16)hn;
        }
      }
      __syncthreads();
    }
  }

  __syncthreads();
  #pragma unroll
  for (int q = 0; q < 4; q++){
    const float4* tf4 = (const float4*)(thoughts + (size_t)(b0 + q) * 8192);
    float4* of4 = (float4*)(newt + (size_t)(b0 + q) * 8192);
    #pragma unroll
    for (int k2 = 0; k2 < 4; k2++){
      int id4 = tid + k2 * 512;
      int row = id4 >> 5, c4 = (id4 & 31) * 4;
      float4 v = tf4[id4];
      if (dirty[q][row]){
        h4 hv = *(const h4*)&nt16[q][row * 136 + c4];
        v.x = (float)hv.x; v.y = (float)hv.y; v.z = (float)hv.z; v.w = (float)hv.w;
      }
      of4[id4] = v;
    }
  }
}

// ---------------- actor_2 (MFMA f16): 32 rows per block, 256 threads ----------------
// x = relu(concat(thoughts,newt)) (32x256) @ a2w1^T (256->128) + b1 -> (32x128) @ a2w2^T
// (128->64) -> tanh. f16 inputs/weights, f32 accum; no discrete decisions downstream.
__global__ __launch_bounds__(256) void k_actor2(
    const float* __restrict__ thoughts, const float* __restrict__ newt,
    const _Float16* __restrict__ w1h, const float* __restrict__ b1,
    const _Float16* __restrict__ w2h, float* __restrict__ out)
{
  const int b0 = blockIdx.x * 32;
  const int tid = threadIdx.x;
  const int w = tid >> 6, lane = tid & 63, lr = lane & 15, hi = lane >> 4;
  const int mt = w & 1, nb = (w >> 1) << 6;

  __shared__ __align__(16) _Float16 Xc[32 * 264];   // relu(concat) f16, padded (16896 B)
  __shared__ __align__(16) _Float16 Ys[32 * 136];   // hidden f16, padded (8704 B)

  #pragma unroll
  for (int k2 = 0; k2 < 8; k2++){
    int id4 = tid + k2 * 256;              // f4 index over 32 rows x 64 f4
    int row = id4 >> 6, c4 = (id4 & 63) * 4;
    const float* src = (c4 < 128) ? (thoughts + (size_t)(b0 + row) * 128 + c4)
                                  : (newt + (size_t)(b0 + row) * 128 + (c4 - 128));
    float4 v = *(const float4*)src;
    *(h4*)&Xc[row * 264 + c4] = pack_h4_relu(v);
  }
  __syncthreads();

  // GEMM1: wave (mt, nb): rows mt*16.., cols nb..nb+63
  {
    h8 Af[8];
    #pragma unroll
    for (int kt = 0; kt < 8; kt++)
      Af[kt] = *(const h8*)&Xc[(mt * 16 + lr) * 264 + kt * 32 + (hi << 3)];
    #pragma unroll
    for (int ni = 0; ni < 4; ni++){
      const int n = nb + ni * 16 + lr;
      const _Float16* wr = w1h + (size_t)n * 256 + (hi << 3);
      f4 acc = {0.0f, 0.0f, 0.0f, 0.0f};
      #pragma unroll
      for (int kt = 0; kt < 8; kt++){
        h8 bfr = *(const h8*)(wr + kt * 32);
        acc = __builtin_amdgcn_mfma_f32_16x16x32_f16(Af[kt], bfr, acc, 0, 0, 0);
      }
      const float bb = b1[n];
      #pragma unroll
      for (int r = 0; r < 4; r++){
        int row = mt * 16 + (hi << 2) + r;
        Ys[row * 136 + n] = (_Float16)(acc[r] + bb);
      }
    }
  }
  __syncthreads();

  // GEMM2: wave (mt, ni0): rows mt*16.., cols (ni0..ni0+1)*16
  {
    const int ni0 = (w >> 1) << 1;
    h8 Ag[4];
    #pragma unroll
    for (int kt = 0; kt < 4; kt++)
      Ag[kt] = *(const h8*)&Ys[(mt * 16 + lr) * 136 + kt * 32 + (hi << 3)];
    #pragma unroll
    for (int nj = 0; nj < 2; nj++){
      const int n = (ni0 + nj) * 16 + lr;
      const _Float16* wr = w2h + (size_t)n * 128 + (hi << 3);
      f4 acc = {0.0f, 0.0f, 0.0f, 0.0f};
      #pragma unroll
      for (int kt = 0; kt < 4; kt++){
        h8 bfr = *(const h8*)(wr + kt * 32);
        acc = __builtin_amdgcn_mfma_f32_16x16x32_f16(Ag[kt], bfr, acc, 0, 0, 0);
      }
      #pragma unroll
      for (int r = 0; r < 4; r++){
        int row = mt * 16 + (hi << 2) + r;
        out[(size_t)(b0 + row) * 64 + n] = ftanh(acc[r]);
      }
    }
  }
}

extern "C" void kernel_launch(void* const* d_in, const int* in_sizes, int n_in,
                              void* d_out, int out_size, void* d_ws, size_t ws_size,
                              hipStream_t stream)
{
  const float* obs  = (const float*)d_in[0];
  const float* w1   = (const float*)d_in[1];
  const float* b1   = (const float*)d_in[2];
  const float* lng  = (const float*)d_in[3];
  const float* lnb  = (const float*)d_in[4];
  const float* w2   = (const float*)d_in[5];
  const float* b2   = (const float*)d_in[6];
  const float* aw1  = (const float*)d_in[7];
  const float* ab1  = (const float*)d_in[8];
  const float* aw2  = (const float*)d_in[9];
  const float* ab2  = (const float*)d_in[10];
  const float* aw3  = (const float*)d_in[11];
  const float* ab3  = (const float*)d_in[12];
  const float* wihf = (const float*)d_in[13];
  const float* whhf = (const float*)d_in[14];
  const float* bihf = (const float*)d_in[15];
  const float* bhhf = (const float*)d_in[16];
  const float* wihb = (const float*)d_in[17];
  const float* whhb = (const float*)d_in[18];
  const float* bihb = (const float*)d_in[19];
  const float* bhhb = (const float*)d_in[20];
  const float* a2w1 = (const float*)d_in[21];
  const float* a2b1 = (const float*)d_in[22];
  const float* a2w2 = (const float*)d_in[23];

  float* thoughts = (float*)d_ws;                       // 33.5 MB
  float* newt     = thoughts + (size_t)ROWS * 128;      // 33.5 MB
  int*   isinit   = (int*)(newt + (size_t)ROWS * 128);  // 256 KB
  int*   idxb     = isinit + ROWS;                      // 2 MB
  _Float16* w1h   = (_Float16*)(idxb + (size_t)ROWS * 8);  // 64 KB
  _Float16* w2h   = w1h + 32768;                           // 16 KB

  hipLaunchKernelGGL(k_cvt, dim3(128), dim3(256), 0, stream, a2w1, a2w2, w1h, w2h);
  hipLaunchKernelGGL(k_actor1, dim3(ROWS / 8), dim3(128), 0, stream,
                     obs, w1, b1, lng, lnb, w2, b2, aw1, ab1, aw2, ab2, aw3, ab3,
                     thoughts, isinit);
  hipLaunchKernelGGL(k_groups, dim3(NB), dim3(256), 0, stream, thoughts, idxb);
  hipLaunchKernelGGL(k_scan, dim3(NB / 4), dim3(512), 0, stream,
                     thoughts, isinit, idxb,
                     wihf, whhf, bihf, bhhf, wihb, whhb, bihb, bhhb, newt);
  hipLaunchKernelGGL(k_actor2, dim3(ROWS / 32), dim3(256), 0, stream,
                     thoughts, newt, w1h, a2b1, w2h, (float*)d_out);
}

// Round 10
// 884.915 us; speedup vs baseline: 1.1736x; 1.0283x over previous
//
#include <hip/hip_runtime.h>

typedef unsigned int u32;
typedef unsigned short u16;
typedef unsigned long long u64;
typedef _Float16 h2 __attribute__((ext_vector_type(2)));
typedef _Float16 h4 __attribute__((ext_vector_type(4)));
typedef _Float16 h8 __attribute__((ext_vector_type(8)));
typedef float f4 __attribute__((ext_vector_type(4)));

#define ROWS 65536   // B*A
#define NB 1024
#define NA 64

__device__ __forceinline__ float dot4(float4 w, float4 x){
  return w.x*x.x + w.y*x.y + w.z*x.z + w.w*x.w;
}
__device__ __forceinline__ h2 u32_h2(u32 v){ union { u32 u; h2 h; } x; x.u = v; return x.h; }
__device__ __forceinline__ h2 pack_h2(float a, float b){ h2 r; r.x = (_Float16)a; r.y = (_Float16)b; return r; }
__device__ __forceinline__ h4 pack_h4(float4 v){
  h4 r; r.x=(_Float16)v.x; r.y=(_Float16)v.y; r.z=(_Float16)v.z; r.w=(_Float16)v.w; return r;
}
__device__ __forceinline__ h4 pack_h4_relu(float4 v){
  h4 r; r.x=(_Float16)fmaxf(v.x,0.f); r.y=(_Float16)fmaxf(v.y,0.f);
  r.z=(_Float16)fmaxf(v.z,0.f); r.w=(_Float16)fmaxf(v.w,0.f); return r;
}
// fast sigmoid/tanh on v_exp_f32 + v_rcp_f32 (~1 ulp each; threshold is 1.1e-2)
__device__ __forceinline__ float fsig(float z){
  float e = __builtin_amdgcn_exp2f(-1.44269504f * z);
  return __builtin_amdgcn_rcpf(1.0f + e);
}
__device__ __forceinline__ float ftanh(float z){
  float e = __builtin_amdgcn_exp2f(2.885390082f * z);
  return 1.0f - 2.0f * __builtin_amdgcn_rcpf(1.0f + e);
}
__device__ __forceinline__ h8 load8f(const float* p){
  float4 a = *(const float4*)p;
  float4 b = *(const float4*)(p + 4);
  h8 r;
  r[0] = (_Float16)a.x; r[1] = (_Float16)a.y; r[2] = (_Float16)a.z; r[3] = (_Float16)a.w;
  r[4] = (_Float16)b.x; r[5] = (_Float16)b.y; r[6] = (_Float16)b.z; r[7] = (_Float16)b.w;
  return r;
}

// ---------------- weight f16 pre-convert (actor_2 weights) ----------------
__global__ __launch_bounds__(256) void k_cvt(
    const float* __restrict__ a2w1, const float* __restrict__ a2w2,
    _Float16* __restrict__ w1h, _Float16* __restrict__ w2h)
{
  int i = blockIdx.x * 256 + threadIdx.x;
  if (i < 32768) w1h[i] = (_Float16)a2w1[i];
  if (i < 8192)  w2h[i] = (_Float16)a2w2[i];
}

// ---------------- actor_1 + attention: 8 rows per block, 128 threads ----------------
// kept f32/VALU: feeds the DISCRETE decisions (isinit threshold, K-nearest argsort) where
// f16 rounding (~1e-3) could flip group membership and blow up absmax.
// v11: attention phases use ALL 128 threads (t>>6 = row-half, t&63 = feature) instead of
// idling t>=64; per-output summation order unchanged -> bitwise identical results.
__global__ __launch_bounds__(128) void k_actor1(
    const float* __restrict__ obs, const float* __restrict__ w1, const float* __restrict__ b1,
    const float* __restrict__ lng, const float* __restrict__ lnb,
    const float* __restrict__ w2, const float* __restrict__ b2,
    const float* __restrict__ aw1, const float* __restrict__ ab1,
    const float* __restrict__ aw2, const float* __restrict__ ab2,
    const float* __restrict__ aw3, const float* __restrict__ ab3,
    float* __restrict__ thoughts, int* __restrict__ isinit)
{
  const int b0 = blockIdx.x * 8;
  const int t = threadIdx.x;
  __shared__ float4 xs[8][64];     // 8 obs rows (256 f32 each)
  __shared__ float hs[8][128];     // relu(LN(h))
  __shared__ float tb[8][128];     // thoughts
  __shared__ float ab[8][64];
  __shared__ float a2b[8][64];
  __shared__ float red[8][4];

  { const float4* og = (const float4*)(obs + (size_t)b0 * 256);
    #pragma unroll
    for (int j = 0; j < 4; j++){ int p = j * 128 + t; xs[p >> 6][p & 63] = og[p]; } }
  __syncthreads();

  // h = obs @ W1^T + b1   (thread t owns output feature t, streams W1 row t)
  float acc[8];
  #pragma unroll
  for (int r = 0; r < 8; r++) acc[r] = b1[t];
  { const float4* wr = (const float4*)(w1 + (size_t)t * 256);
    for (int j = 0; j < 64; j++){
      float4 w = wr[j];
      #pragma unroll
      for (int r = 0; r < 8; r++) acc[r] += dot4(w, xs[r][j]);
    } }

  // LayerNorm over 128 features (block = 2 waves)
  #pragma unroll
  for (int r = 0; r < 8; r++){
    float s = acc[r], s2 = acc[r] * acc[r];
    #pragma unroll
    for (int off = 32; off > 0; off >>= 1){ s += __shfl_down(s, off); s2 += __shfl_down(s2, off); }
    if ((t & 63) == 0){ red[r][t >> 6] = s; red[r][2 + (t >> 6)] = s2; }
  }
  __syncthreads();
  const float g_ = lng[t], bb_ = lnb[t];
  #pragma unroll
  for (int r = 0; r < 8; r++){
    float mu  = (red[r][0] + red[r][1]) * (1.0f/128.0f);
    float var = (red[r][2] + red[r][3]) * (1.0f/128.0f) - mu * mu;
    hs[r][t] = fmaxf((acc[r] - mu) * rsqrtf(var + 1e-5f) * g_ + bb_, 0.0f);
  }
  __syncthreads();

  // thoughts = relu(h) @ W2^T + b2
  float acc2[8];
  #pragma unroll
  for (int r = 0; r < 8; r++) acc2[r] = b2[t];
  { const float4* wr = (const float4*)(w2 + (size_t)t * 128);
    for (int j = 0; j < 32; j++){
      float4 w = wr[j];
      #pragma unroll
      for (int r = 0; r < 8; r++) acc2[r] += dot4(w, ((const float4*)hs[r])[j]);
    } }
  #pragma unroll
  for (int r = 0; r < 8; r++){
    thoughts[(size_t)(b0 + r) * 128 + t] = acc2[r];
    tb[r][t] = acc2[r];
  }
  __syncthreads();

  // attention MLP — all 128 threads: rh = row-half, fa = feature
  const int rh = t >> 6, fa = t & 63;
  {
    float a[4];
    #pragma unroll
    for (int r = 0; r < 4; r++) a[r] = ab1[fa];
    const float4* wr = (const float4*)(aw1 + (size_t)fa * 128);
    for (int j = 0; j < 32; j++){
      float4 w = wr[j];
      #pragma unroll
      for (int r = 0; r < 4; r++) a[r] += dot4(w, ((const float4*)tb[rh * 4 + r])[j]);
    }
    #pragma unroll
    for (int r = 0; r < 4; r++) ab[rh * 4 + r][fa] = fmaxf(a[r], 0.0f);
  }
  __syncthreads();
  {
    float a[4];
    #pragma unroll
    for (int r = 0; r < 4; r++) a[r] = ab2[fa];
    const float4* wr = (const float4*)(aw2 + (size_t)fa * 64);
    for (int j = 0; j < 16; j++){
      float4 w = wr[j];
      #pragma unroll
      for (int r = 0; r < 4; r++) a[r] += dot4(w, ((const float4*)ab[rh * 4 + r])[j]);
    }
    #pragma unroll
    for (int r = 0; r < 4; r++) a2b[rh * 4 + r][fa] = fmaxf(a[r], 0.0f);
  }
  __syncthreads();
  if (t < 8){
    float p = ab3[0];
    for (int j = 0; j < 64; j++) p += aw3[j] * a2b[t][j];
    isinit[b0 + t] = (p > 0.0f) ? 1 : 0;   // sigmoid(p) > 0.5  <=>  p > 0
  }
}

// ---------------- K-nearest groups: one block per batch ----------------
__global__ __launch_bounds__(256) void k_groups(
    const float* __restrict__ thoughts, int* __restrict__ idxout)
{
  const int b = blockIdx.x;
  const int tid = threadIdx.x;
  __shared__ float T[64 * 130];
  __shared__ float sq[64];
  for (int p = tid; p < 8192; p += 256){
    T[(p >> 7) * 130 + (p & 127)] = thoughts[(size_t)b * 8192 + p];
  }
  __syncthreads();
  if (tid < 64){
    const float2* tj = (const float2*)&T[tid * 130];
    float s = 0.0f;
    #pragma unroll 8
    for (int k = 0; k < 64; k++){ float2 v = tj[k]; s += v.x*v.x + v.y*v.y; }
    sq[tid] = s;
  }
  __syncthreads();
  const int lane = tid & 63;
  const int wv = tid >> 6;
  const float2* tj = (const float2*)&T[lane * 130];
  const float sqj = sq[lane];
  for (int ii = 0; ii < 16; ii++){
    const int i = wv * 16 + ii;
    const float2* ti = (const float2*)&T[i * 130];
    float dot = 0.0f;
    #pragma unroll 8
    for (int k = 0; k < 64; k++){ float2 a = ti[k]; float2 c = tj[k]; dot += a.x*c.x + a.y*c.y; }
    float d = fmaxf(sq[i] + sqj - 2.0f*dot, 0.0f);   // clamp keeps uint-compare == float-compare
    u64 key = (((u64)__float_as_uint(d)) << 32) | (u32)lane;
    u64 mask = 0;
    for (int q = 0; q < 8; q++){
      u64 m = key;
      #pragma unroll
      for (int off = 32; off > 0; off >>= 1){ u64 o = __shfl_xor(m, off); if (o < m) m = o; }
      mask |= 1ull << (u32)(m & 63u);
      if (key == m) key = ~0ull;
    }
    if (lane == 0){
      u64 mm = mask;
      int base = (b * 64 + i) * 8;
      #pragma unroll
      for (int q = 0; q < 8; q++){ int j = (int)__builtin_ctzll(mm); mm &= mm - 1; idxout[base + q] = j; }
    }
  }
}

// ---------------- sequential gather -> bi-LSTM -> scatter: FOUR batches per block ----------------
// v11 = v10 (4-batch row-packed recurrence MFMA) with the step body's redundant VALU cut:
//  * hi-group = batch specialization: lane (lr,hi) extracts batch hi's z (constant-index
//    selects), computes ONE gate set, tracks ONE c, and writes batch hi's hn. v10 computed
//    the gates 4x redundantly across hi groups (only hi==0 wrote) -> VALUBusy 42% was the
//    interval bound. Coverage identical: wave (dir,wsub) still serves 16 l x 4 batches.
//  * Zx in f32 LDS (64 KB, total ~143 KB, same 1 block/CU): no pack in phase A, no 16
//    f16->f32 unpacks per step for MFMA C-init; slightly MORE accurate than f16 round-trip.
// Inactive-batch invariant (carried from v10): stale Zx/hb16 are finite; lanes of an
// inactive batch compute garbage gates but writes are fq-guarded; c resets per round.
// MFMA conventions (verified v3-v10): A row = lane&15, B col = lane&15,
// k = kt*32 + (lane>>4)*8 + j, C: col = lane&15, row = (lane>>4)*4 + reg.
__global__ __launch_bounds__(512, 2) void k_scan(
    const float* __restrict__ thoughts, const int* __restrict__ isinit, const int* __restrict__ idx,
    const float* __restrict__ wihf, const float* __restrict__ whhf,
    const float* __restrict__ bihf, const float* __restrict__ bhhf,
    const float* __restrict__ wihb, const float* __restrict__ whhb,
    const float* __restrict__ bihb, const float* __restrict__ bhhb,
    float* __restrict__ newt)
{
  const int b0   = blockIdx.x * 4;
  const int tid  = threadIdx.x;
  const int w    = tid >> 6;          // wave 0..7
  const int lane = tid & 63;
  const int dir  = w >> 2;            // waves 0-3 fwd, 4-7 bwd
  const int wsub = w & 3;             // phase-A gate == phase-B l-slice
  const int lr   = lane & 15;
  const int hi   = lane >> 4;

  __shared__ __align__(16) _Float16 nt16[4][64 * 136]; // f16 state mirrors (4 x 17408 B)
  __shared__ __align__(16) float Zx32[4][2*8*64*4];    // input projections f32 (4 x 16384 B)
  __shared__ __align__(16) _Float16 hb16[4][2][72];    // h states, 8-bank q-skew (1152 B)
  __shared__ int gall[4][512];
  __shared__ int flags[4][64];
  __shared__ int dirty[4][64];

  const float* wih = dir ? wihb : wihf;
  const float* whh = dir ? whhb : whhf;

  // phase-A B fragments: Wih[(wsub*64 + ni*16 + lr)][kt*32 + hi*8 + j]  (64 VGPR)
  h8 Bf[4][4];
  #pragma unroll
  for (int ni = 0; ni < 4; ni++){
    const float* wr = wih + (size_t)((wsub << 6) + (ni << 4) + lr) * 128 + (hi << 3);
    #pragma unroll
    for (int kt = 0; kt < 4; kt++) Bf[ni][kt] = load8f(wr + kt * 32);
    __builtin_amdgcn_sched_barrier(0);   // cap init liveness
  }
  // phase-B B fragments: Whh[(gg*64 + wsub*16 + lr)][kt*32 + hi*8 + j]  (32 VGPR)
  h8 Bh[4][2];
  #pragma unroll
  for (int gg = 0; gg < 4; gg++){
    const float* wr = whh + (size_t)((gg << 6) + (wsub << 4) + lr) * 64 + (hi << 3);
    #pragma unroll
    for (int kt = 0; kt < 2; kt++) Bh[gg][kt] = load8f(wr + kt * 32);
    __builtin_amdgcn_sched_barrier(0);
  }
  // bias for the Zx columns this lane writes (batch-independent)
  float biasl[4];
  {
    const float* bih = dir ? bihb : bihf;
    const float* bhh = dir ? bhhb : bhhf;
    #pragma unroll
    for (int ni = 0; ni < 4; ni++){
      int n = (wsub << 6) + (ni << 4) + lr;
      biasl[ni] = bih[n] + bhh[n];
    }
  }

  #pragma unroll
  for (int q = 0; q < 4; q++){
    const float4* tf4 = (const float4*)(thoughts + (size_t)(b0 + q) * 8192);
    #pragma unroll
    for (int k2 = 0; k2 < 4; k2++){
      int id4 = tid + k2 * 512;                 // f4 index, 2048 per batch (32 f4 per row)
      float4 v = tf4[id4];
      *(h4*)&nt16[q][(id4 >> 5) * 136 + (id4 & 31) * 4] = pack_h4(v);
    }
  }
  #pragma unroll
  for (int k2 = 0; k2 < 4; k2++){
    int p = tid + k2 * 512;
    gall[p >> 9][p & 511] = idx[(size_t)b0 * 512 + p];
  }
  if (tid < 256){ int q = tid >> 6, j = tid & 63;
    flags[q][j] = isinit[(b0 + q) * 64 + j]; dirty[q][j] = 0; }
  if (tid < 288) ((h2*)hb16)[tid] = pack_h2(0.0f, 0.0f);   // zero h states (576 f16)
  __syncthreads();

  #pragma unroll 1
  for (int i = 0; i < 64; i++){
    const int f0 = flags[0][i], f1 = flags[1][i], f2 = flags[2][i], f3 = flags[3][i];
    if (!(f0 | f1 | f2 | f3)) continue;           // block-uniform
    if (tid < 32){ int q = tid >> 3, j = tid & 7;
      int fq = (q == 0) ? f0 : (q == 1) ? f1 : (q == 2) ? f2 : f3;
      if (fq) dirty[q][gall[q][i * 8 + j]] = 1; }

    // ---- phase A: two batch-pairs, each with 2-batch A-row packing (rows 0-7/8-15) ----
    #pragma unroll
    for (int pr = 0; pr < 2; pr++){
      const int fp = pr ? (f2 | f3) : (f0 | f1);
      if (fp){
        const int qa = (pr << 1) + (lr >> 3);
        const int grow = gall[qa][i * 8 + (lr & 7)];
        h8 Af[4];
        #pragma unroll
        for (int kt = 0; kt < 4; kt++)
          Af[kt] = *(const h8*)&nt16[qa][grow * 136 + kt * 32 + (hi << 3)];
        const int qo = (pr << 1) + (hi >> 1), t0 = (hi & 1) << 2;
        #pragma unroll
        for (int ni = 0; ni < 4; ni++){
          f4 acc = {0.0f, 0.0f, 0.0f, 0.0f};
          #pragma unroll
          for (int kt = 0; kt < 4; kt++)
            acc = __builtin_amdgcn_mfma_f32_16x16x32_f16(Af[kt], Bf[ni][kt], acc, 0, 0, 0);
          const int lp = (ni << 4) + lr;
          #pragma unroll
          for (int r = 0; r < 4; r++)
            Zx32[qo][(((dir << 3) + t0 + r) * 64 + lp) * 4 + wsub] = acc[r] + biasl[ni];
        }
      }
    }
    __syncthreads();

    // ---- phase B: 8 steps; ONE packed MFMA set serves all 4 batches; lane's gate work
    //      specialized to batch hi (no redundant gate computation across hi groups) ----
    float c = 0.0f;
    const int fq = (hi == 0) ? f0 : (hi == 1) ? f1 : (hi == 2) ? f2 : f3;
    #pragma unroll
    for (int s = 0; s < 8; s++){
      const int tt = dir ? (7 - s) : s;
      const int zoff = (((dir << 3) + tt) * 64 + (wsub << 4) + lr) * 4;
      float4 zq0 = *(const float4*)&Zx32[0][zoff];
      float4 zq1 = *(const float4*)&Zx32[1][zoff];
      float4 zq2 = *(const float4*)&Zx32[2][zoff];
      float4 zq3 = *(const float4*)&Zx32[3][zoff];
      // C-init: reg r = batch r's Zx for this lane's l (gates i,f,g,o -> A0..A3)
      f4 A0 = {zq0.x, zq1.x, zq2.x, zq3.x};
      f4 A1 = {zq0.y, zq1.y, zq2.y, zq3.y};
      f4 A2 = {zq0.z, zq1.z, zq2.z, zq3.z};
      f4 A3 = {zq0.w, zq1.w, zq2.w, zq3.w};
      if (s > 0){
        // A row r = batch (r&3)'s h: lane supplies row lr -> batch lr&3, k-slice hi*8+j
        const int qa = lr & 3;
        h8 a0 = *(const h8*)&hb16[qa][dir][(hi << 3)];
        h8 a1 = *(const h8*)&hb16[qa][dir][32 + (hi << 3)];
        A0 = __builtin_amdgcn_mfma_f32_16x16x32_f16(a0, Bh[0][0], A0, 0, 0, 0);
        A0 = __builtin_amdgcn_mfma_f32_16x16x32_f16(a1, Bh[0][1], A0, 0, 0, 0);
        A1 = __builtin_amdgcn_mfma_f32_16x16x32_f16(a0, Bh[1][0], A1, 0, 0, 0);
        A1 = __builtin_amdgcn_mfma_f32_16x16x32_f16(a1, Bh[1][1], A1, 0, 0, 0);
        A2 = __builtin_amdgcn_mfma_f32_16x16x32_f16(a0, Bh[2][0], A2, 0, 0, 0);
        A2 = __builtin_amdgcn_mfma_f32_16x16x32_f16(a1, Bh[2][1], A2, 0, 0, 0);
        A3 = __builtin_amdgcn_mfma_f32_16x16x32_f16(a0, Bh[3][0], A3, 0, 0, 0);
        A3 = __builtin_amdgcn_mfma_f32_16x16x32_f16(a1, Bh[3][1], A3, 0, 0, 0);
      }
      // lane handles batch hi only (constant-index selects; no dynamic vector index)
      float z0 = (hi == 0) ? A0[0] : (hi == 1) ? A0[1] : (hi == 2) ? A0[2] : A0[3];
      float z1 = (hi == 0) ? A1[0] : (hi == 1) ? A1[1] : (hi == 2) ? A1[2] : A1[3];
      float z2 = (hi == 0) ? A2[0] : (hi == 1) ? A2[1] : (hi == 2) ? A2[2] : A2[3];
      float z3 = (hi == 0) ? A3[0] : (hi == 1) ? A3[1] : (hi == 2) ? A3[2] : A3[3];
      float fi = fsig(z0);
      float ff = fsig(z1);
      float fg = ftanh(z2);
      float fo = fsig(z3);
      c = ff * c + fi * fg;
      float hn = fo * ftanh(c);
      if (fq){
        hb16[hi][dir][(wsub << 4) + lr] = (_Float16)hn;
        nt16[hi][gall[hi][i * 8 + tt] * 136 + (dir << 6) + (wsub << 4) + lr] = (_Float16)hn;
      }
      __syncthreads();
    }
  }

  __syncthreads();
  #pragma unroll
  for (int q = 0; q < 4; q++){
    const float4* tf4 = (const float4*)(thoughts + (size_t)(b0 + q) * 8192);
    float4* of4 = (float4*)(newt + (size_t)(b0 + q) * 8192);
    #pragma unroll
    for (int k2 = 0; k2 < 4; k2++){
      int id4 = tid + k2 * 512;
      int row = id4 >> 5, c4 = (id4 & 31) * 4;
      float4 v = tf4[id4];
      if (dirty[q][row]){
        h4 hv = *(const h4*)&nt16[q][row * 136 + c4];
        v.x = (float)hv.x; v.y = (float)hv.y; v.z = (float)hv.z; v.w = (float)hv.w;
      }
      of4[id4] = v;
    }
  }
}

// ---------------- actor_2 (MFMA f16): 32 rows per block, 256 threads ----------------
// x = relu(concat(thoughts,newt)) (32x256) @ a2w1^T (256->128) + b1 -> (32x128) @ a2w2^T
// (128->64) -> tanh. f16 inputs/weights, f32 accum; no discrete decisions downstream.
__global__ __launch_bounds__(256) void k_actor2(
    const float* __restrict__ thoughts, const float* __restrict__ newt,
    const _Float16* __restrict__ w1h, const float* __restrict__ b1,
    const _Float16* __restrict__ w2h, float* __restrict__ out)
{
  const int b0 = blockIdx.x * 32;
  const int tid = threadIdx.x;
  const int w = tid >> 6, lane = tid & 63, lr = lane & 15, hi = lane >> 4;
  const int mt = w & 1, nb = (w >> 1) << 6;

  __shared__ __align__(16) _Float16 Xc[32 * 264];   // relu(concat) f16, padded (16896 B)
  __shared__ __align__(16) _Float16 Ys[32 * 136];   // hidden f16, padded (8704 B)

  #pragma unroll
  for (int k2 = 0; k2 < 8; k2++){
    int id4 = tid + k2 * 256;              // f4 index over 32 rows x 64 f4
    int row = id4 >> 6, c4 = (id4 & 63) * 4;
    const float* src = (c4 < 128) ? (thoughts + (size_t)(b0 + row) * 128 + c4)
                                  : (newt + (size_t)(b0 + row) * 128 + (c4 - 128));
    float4 v = *(const float4*)src;
    *(h4*)&Xc[row * 264 + c4] = pack_h4_relu(v);
  }
  __syncthreads();

  // GEMM1: wave (mt, nb): rows mt*16.., cols nb..nb+63
  {
    h8 Af[8];
    #pragma unroll
    for (int kt = 0; kt < 8; kt++)
      Af[kt] = *(const h8*)&Xc[(mt * 16 + lr) * 264 + kt * 32 + (hi << 3)];
    #pragma unroll
    for (int ni = 0; ni < 4; ni++){
      const int n = nb + ni * 16 + lr;
      const _Float16* wr = w1h + (size_t)n * 256 + (hi << 3);
      f4 acc = {0.0f, 0.0f, 0.0f, 0.0f};
      #pragma unroll
      for (int kt = 0; kt < 8; kt++){
        h8 bfr = *(const h8*)(wr + kt * 32);
        acc = __builtin_amdgcn_mfma_f32_16x16x32_f16(Af[kt], bfr, acc, 0, 0, 0);
      }
      const float bb = b1[n];
      #pragma unroll
      for (int r = 0; r < 4; r++){
        int row = mt * 16 + (hi << 2) + r;
        Ys[row * 136 + n] = (_Float16)(acc[r] + bb);
      }
    }
  }
  __syncthreads();

  // GEMM2: wave (mt, ni0): rows mt*16.., cols (ni0..ni0+1)*16
  {
    const int ni0 = (w >> 1) << 1;
    h8 Ag[4];
    #pragma unroll
    for (int kt = 0; kt < 4; kt++)
      Ag[kt] = *(const h8*)&Ys[(mt * 16 + lr) * 136 + kt * 32 + (hi << 3)];
    #pragma unroll
    for (int nj = 0; nj < 2; nj++){
      const int n = (ni0 + nj) * 16 + lr;
      const _Float16* wr = w2h + (size_t)n * 128 + (hi << 3);
      f4 acc = {0.0f, 0.0f, 0.0f, 0.0f};
      #pragma unroll
      for (int kt = 0; kt < 4; kt++){
        h8 bfr = *(const h8*)(wr + kt * 32);
        acc = __builtin_amdgcn_mfma_f32_16x16x32_f16(Ag[kt], bfr, acc, 0, 0, 0);
      }
      #pragma unroll
      for (int r = 0; r < 4; r++){
        int row = mt * 16 + (hi << 2) + r;
        out[(size_t)(b0 + row) * 64 + n] = ftanh(acc[r]);
      }
    }
  }
}

extern "C" void kernel_launch(void* const* d_in, const int* in_sizes, int n_in,
                              void* d_out, int out_size, void* d_ws, size_t ws_size,
                              hipStream_t stream)
{
  const float* obs  = (const float*)d_in[0];
  const float* w1   = (const float*)d_in[1];
  const float* b1   = (const float*)d_in[2];
  const float* lng  = (const float*)d_in[3];
  const float* lnb  = (const float*)d_in[4];
  const float* w2   = (const float*)d_in[5];
  const float* b2   = (const float*)d_in[6];
  const float* aw1  = (const float*)d_in[7];
  const float* ab1  = (const float*)d_in[8];
  const float* aw2  = (const float*)d_in[9];
  const float* ab2  = (const float*)d_in[10];
  const float* aw3  = (const float*)d_in[11];
  const float* ab3  = (const float*)d_in[12];
  const float* wihf = (const float*)d_in[13];
  const float* whhf = (const float*)d_in[14];
  const float* bihf = (const float*)d_in[15];
  const float* bhhf = (const float*)d_in[16];
  const float* wihb = (const float*)d_in[17];
  const float* whhb = (const float*)d_in[18];
  const float* bihb = (const float*)d_in[19];
  const float* bhhb = (const float*)d_in[20];
  const float* a2w1 = (const float*)d_in[21];
  const float* a2b1 = (const float*)d_in[22];
  const float* a2w2 = (const float*)d_in[23];

  float* thoughts = (float*)d_ws;                       // 33.5 MB
  float* newt     = thoughts + (size_t)ROWS * 128;      // 33.5 MB
  int*   isinit   = (int*)(newt + (size_t)ROWS * 128);  // 256 KB
  int*   idxb     = isinit + ROWS;                      // 2 MB
  _Float16* w1h   = (_Float16*)(idxb + (size_t)ROWS * 8);  // 64 KB
  _Float16* w2h   = w1h + 32768;                           // 16 KB

  hipLaunchKernelGGL(k_cvt, dim3(128), dim3(256), 0, stream, a2w1, a2w2, w1h, w2h);
  hipLaunchKernelGGL(k_actor1, dim3(ROWS / 8), dim3(128), 0, stream,
                     obs, w1, b1, lng, lnb, w2, b2, aw1, ab1, aw2, ab2, aw3, ab3,
                     thoughts, isinit);
  hipLaunchKernelGGL(k_groups, dim3(NB), dim3(256), 0, stream, thoughts, idxb);
  hipLaunchKernelGGL(k_scan, dim3(NB / 4), dim3(512), 0, stream,
                     thoughts, isinit, idxb,
                     wihf, whhf, bihf, bhhf, wihb, whhb, bihb, bhhb, newt);
  hipLaunchKernelGGL(k_actor2, dim3(ROWS / 32), dim3(256), 0, stream,
                     thoughts, newt, w1h, a2b1, w2h, (float*)d_out);
}